// Round 11
// baseline (119.686 us; speedup 1.0000x reference)
//
#include <hip/hip_runtime.h>
#include <cstdint>
#include <cstddef>

// Problem constants: B=4, C=256, H=60, W=80, N=4800
#define BQ 4
#define CDIM 256
#define HH 60
#define WW 80
#define NP 4800
#define NPAD 4864          // 38*128
#define BT 128             // tile rows (t, A = tar)
#define BJ 128             // tile cols (j, B = ref)
#define NTT 38             // t tiles (128)
#define NTJ 38             // j tiles (128)
#define NBLK (BQ * NTJ * NTT)   // 5776, %8==0

typedef float f32x4 __attribute__((ext_vector_type(4)));
typedef unsigned short u16x8 __attribute__((ext_vector_type(8)));
typedef long longx2 __attribute__((ext_vector_type(2)));

// ---------------- ws layout (bytes) ----------------
#define WS_DEST 0              // bf16 2*4*4800*256*2 = 19,660,800 (dead after k_sample)
#define WS_PART 0              // uint2 4*4800*38*8 = 5,836,800 (aliases desT)
#define WS_REFB 19660800       // bf16 4*4864*256*2 = 9,961,472 (for k_loss)
#define WS_TARB 29622272       // bf16                9,961,472
#define WS_REFQ 39583744       // fp8 4*4864*256 = 4,980,736 (for GEMM, k-permuted)
#define WS_TARQ 44564480       // fp8                4,980,736
#define WS_LOSS 49545216       // f32 19200 = 76,800
#define WS_REC  49622016       // f32 19200
// end 49,698,816

#define GLD16(dst, src) __builtin_amdgcn_global_load_lds( \
    (const __attribute__((address_space(1))) void*)(src), \
    (__attribute__((address_space(3))) void*)(dst), 16, 0, 0)

__device__ inline unsigned short f2bf(float f) {
  unsigned int u = __float_as_uint(f);
  return (unsigned short)((u + 0x7FFFu + ((u >> 16) & 1u)) >> 16);  // RNE
}
__device__ inline float bf2f(unsigned short s) {
  return __uint_as_float((unsigned int)s << 16);
}
// f32 -> OCP e4m3fn, RNE, clamp to +-448, subnormals handled
__device__ inline unsigned char f2e4m3(float x) {
  float ax = fminf(fabsf(x), 448.f);
  const unsigned int sign = (__float_as_uint(x) >> 24) & 0x80u;
  if (ax < 0.015625f) {                     // below 2^-6: subnormal (or carry to 0x08)
    const int M = (int)rintf(ax * 512.f);   // 0..8; 8 == 2^-6 encodes as E=1,M=0
    return (unsigned char)(sign | (unsigned int)M);
  }
  unsigned int u = __float_as_uint(ax);
  u += 0x7FFFFu + ((u >> 20) & 1u);         // RNE at mantissa bit 20 (carry ok)
  unsigned int e = (u >> 23) - 120u;        // exp bias 127 -> 7
  unsigned int m = (u >> 20) & 7u;
  if (e >= 16u) { e = 15u; m = 6u; }        // clamp to 448 (rounding overshoot)
  return (unsigned char)(sign | (e << 3) | m);
}

// ---------------- transpose des (C, HW) f32 -> (HW, C) bf16 ----------------
__global__ __launch_bounds__(256)
void k_transpose(const float* __restrict__ src, const float* __restrict__ tgt,
                 unsigned short* __restrict__ desT) {
  __shared__ float tile[64][33];
  const int z = blockIdx.z;  // tensor*4 + b
  const float* in = ((z >> 2) ? tgt : src) + (size_t)(z & 3) * CDIM * NP;
  unsigned short* out = desT + (size_t)z * NP * CDIM;
  const int hw0 = blockIdx.x * 32;
  const int c0 = blockIdx.y * 64;
  const int tx = threadIdx.x, ty = threadIdx.y;
#pragma unroll
  for (int q = 0; q < 8; ++q)
    tile[ty + q * 8][tx] = in[(size_t)(c0 + ty + q * 8) * NP + hw0 + tx];
  __syncthreads();
  const int lt = ty * 32 + tx;
  const int c2 = lt & 7;        // 8 channels each
  const int hw = lt >> 3;       // 0..31
  u16x8 o;
#pragma unroll
  for (int k = 0; k < 8; ++k) o[k] = f2bf(tile[c2 * 8 + k][hw]);
  *(u16x8*)(out + (size_t)(hw0 + hw) * CDIM + c0 + c2 * 8) = o;
}

// ---------------- bilinear sample + L2 normalize -> bf16 rows + k-permuted fp8 rows ----------------
// fp8 rows store byte (kb*64 + ks*32 + h*8 + b) at position (kb*64 + h*16 + ks*8 + b):
// one contiguous 16-B read at offset h*16 then yields both K=32 MFMA slices.
// Same permutation on ref and tar -> dot products unchanged.
__global__ __launch_bounds__(256)
void k_sample(const unsigned short* __restrict__ desT,
              const float* __restrict__ spts, const float* __restrict__ tpts,
              unsigned short* __restrict__ refB, unsigned short* __restrict__ tarB,
              unsigned char* __restrict__ refQ, unsigned char* __restrict__ tarQ) {
  const int w = threadIdx.x >> 6, lane = threadIdx.x & 63;
  const int n = blockIdx.x * 4 + w;         // 0..NPAD-1
  const int b = blockIdx.y;
  const int tensor = blockIdx.z;            // 0: ref, 1: tar
  unsigned short* outRowB = (tensor ? tarB : refB) + ((size_t)b * NPAD + n) * CDIM;
  unsigned char*  outRowQ = (tensor ? tarQ : refQ) + ((size_t)b * NPAD + n) * CDIM;
  const int c0 = lane * 4;
  // permuted uchar4 position (bits: kb[7:6] | h[4:3]->[5:4] | ks[5]->[3] | b[2:0])
  const int dstq = (c0 & 0xC0) | ((c0 & 24) << 1) | ((c0 & 32) >> 2) | (c0 & 7);
  if (n >= NP) {  // zero pad rows (uniform per wave)
    *(ushort4*)(outRowB + c0) = make_ushort4(0, 0, 0, 0);
    *(uchar4*)(outRowQ + dstq) = make_uchar4(0, 0, 0, 0);
    return;
  }
  const float* pts = (tensor ? tpts : spts) + ((size_t)b * NP + n) * 2;
  const float gx = pts[0], gy = pts[1];
  const float x = (gx + 1.f) * ((WW - 1) * 0.5f);
  const float y = (gy + 1.f) * ((HH - 1) * 0.5f);
  float x0f = fminf(fmaxf(floorf(x), 0.f), (float)(WW - 1));
  float y0f = fminf(fmaxf(floorf(y), 0.f), (float)(HH - 1));
  float x1f = fminf(x0f + 1.f, (float)(WW - 1));
  float y1f = fminf(y0f + 1.f, (float)(HH - 1));
  const float wx = x - x0f, wy = y - y0f;
  const int ix0 = (int)x0f, ix1 = (int)x1f, iy0 = (int)y0f, iy1 = (int)y1f;
  const unsigned short* base = desT + (size_t)(tensor * 4 + b) * NP * CDIM + c0;
  const ushort4 u00 = *(const ushort4*)(base + (size_t)(iy0 * WW + ix0) * CDIM);
  const ushort4 u01 = *(const ushort4*)(base + (size_t)(iy0 * WW + ix1) * CDIM);
  const ushort4 u10 = *(const ushort4*)(base + (size_t)(iy1 * WW + ix0) * CDIM);
  const ushort4 u11 = *(const ushort4*)(base + (size_t)(iy1 * WW + ix1) * CDIM);
  const float w00 = (1.f - wx) * (1.f - wy), w01 = wx * (1.f - wy);
  const float w10 = (1.f - wx) * wy,         w11 = wx * wy;
  float4 v;
  v.x = bf2f(u00.x) * w00 + bf2f(u01.x) * w01 + bf2f(u10.x) * w10 + bf2f(u11.x) * w11;
  v.y = bf2f(u00.y) * w00 + bf2f(u01.y) * w01 + bf2f(u10.y) * w10 + bf2f(u11.y) * w11;
  v.z = bf2f(u00.z) * w00 + bf2f(u01.z) * w01 + bf2f(u10.z) * w10 + bf2f(u11.z) * w11;
  v.w = bf2f(u00.w) * w00 + bf2f(u01.w) * w01 + bf2f(u10.w) * w10 + bf2f(u11.w) * w11;
  float s0 = v.x + 1e-8f, s1 = v.y + 1e-8f, s2 = v.z + 1e-8f, s3 = v.w + 1e-8f;
  float sum = s0 * s0 + s1 * s1 + s2 * s2 + s3 * s3;
#pragma unroll
  for (int d = 1; d < 64; d <<= 1) sum += __shfl_xor(sum, d);
  const float inv = 1.f / (sqrtf(sum) + 1e-8f);
  *(ushort4*)(outRowB + c0) =
      make_ushort4(f2bf(v.x * inv), f2bf(v.y * inv), f2bf(v.z * inv), f2bf(v.w * inv));
  const float invq = inv * 16.f;   // scale into e4m3 normal range; dot' = 256*dot
  *(uchar4*)(outRowQ + dstq) =
      make_uchar4(f2e4m3(v.x * invq), f2e4m3(v.y * invq), f2e4m3(v.z * invq), f2e4m3(v.w * invq));
}

// ---------------- fp8 MFMA GEMM (128t x 128j, BK=64) + fused dual argmax ----------------
// Round-11 change: A operand goes global->register directly (double-buffered, the
// k-permuted rows make a lane's fragment one contiguous 16-B read; h-lanes of a row
// coalesce into one 64-B line). Only B flows through LDS (proven zero-conflict
// swizzle) -> LDS-pipe cycles/block drop ~2800 -> ~1800 (round-10's tallest pole).
// launch_bounds (256,3): +32 A-regs would spill at the (256,4) 128-reg cap
// (round-10 ran at 124 = 60 VGPR + 64 AGPR); cap 170 -> 3 blocks/CU.
// T5 setprio around the MFMA cluster (blocks are phase-independent here).
struct Smem {
  char bufs[2][8192];    // B only: [128][64B] per buf
  float2 tc2[128];       // t coords (x,y)
  float2 jc2[128];       // j coords (x,y)
};                       // 18,432 B

__global__ __launch_bounds__(256, 3)
void k_mfma_argmax(const unsigned char* __restrict__ tarQ,
                   const unsigned char* __restrict__ refQ,
                   const float* __restrict__ un, const int* __restrict__ relax,
                   uint2* __restrict__ partial) {
  __shared__ Smem sm;
  const int tid = threadIdx.x;
  const int lane = tid & 63;
  const int wid = tid >> 6;

  // XCD swizzle (5776 % 8 == 0)
  const int bid = blockIdx.x;
  const int item = (bid & 7) * (NBLK / 8) + (bid >> 3);
  const int b = item / (NTJ * NTT);
  const int r2 = item - b * (NTJ * NTT);
  const int jt = r2 / NTT, tt = r2 % NTT;
  const int tbase = tt * BT, jbase = jt * BJ;
  const float* unb = un + (size_t)b * 2 * NP;

  // stage coords into LDS (before first barrier)
  if (tid < 128) {
    const int tg = (tbase + tid < NP) ? tbase + tid : NP - 1;
    sm.tc2[tid] = make_float2(unb[tg], unb[NP + tg]);
  } else {
    const int i2 = tid - 128;
    const int jg = (jbase + i2 < NP) ? jbase + i2 : NP - 1;
    sm.jc2[i2] = make_float2(unb[jg], unb[NP + jg]);
  }

  // B staging: all 4 waves, 32 rows each (rows wid*32 + qq*16 + (lane>>2)).
  // Source slot pre-swizzled: (l&3) ^ ((l>>3)&3) == slot ^ ((row>>1)&3)
  const char* bSrc = (const char*)(refQ + ((size_t)b * NPAD + jbase) * CDIM);
  const int srcSlot = ((lane & 3) ^ ((lane >> 3) & 3)) * 16;
  const char* glB = bSrc + (size_t)(wid * 32 + (lane >> 2)) * 256 + srcSlot;
  const int ldsOffB = wid * 2048;

#define STAGEB(buf, kb) do { \
    char* ldst = sm.bufs[buf] + ldsOffB; \
    const char* gsp = glB + (kb) * 64; \
    GLD16(ldst, gsp); \
    GLD16(ldst + 1024, gsp + 4096); \
  } while (0)

  const int wr = wid >> 1, wc = wid & 1;   // wave tile: 64t x 64j
  const int l15 = lane & 15, h = lane >> 4;
  const int sx = (h ^ ((l15 >> 1) & 3)) << 4;   // swizzled 16-B slot (round-5 pattern)

  // A direct: lane's fragment base (k-permuted rows -> contiguous 16 B per kb)
  const char* aSrc = (const char*)(tarQ + ((size_t)b * NPAD + tbase) * CDIM);
  const char* aLane = aSrc + (size_t)(wr * 64 + l15) * 256 + h * 16;

  f32x4 acc[4][4];
#pragma unroll
  for (int fa = 0; fa < 4; ++fa)
#pragma unroll
    for (int fb = 0; fb < 4; ++fb) acc[fa][fb] = (f32x4){0.f, 0.f, 0.f, 0.f};

  const char* bptr = sm.bufs[0] + (wc * 64 + l15) * 64 + sx;

  longx2 aR[2][4];   // double-buffered A fragments (static indices via full unroll)
#pragma unroll
  for (int fa = 0; fa < 4; ++fa)
    aR[0][fa] = *(const longx2*)(aLane + fa * 4096);
  STAGEB(0, 0);
  __syncthreads();
#pragma unroll
  for (int kb = 0; kb < 4; ++kb) {   // K = 256 = 4 * 64
    const int bo = (kb & 1) * 8192;
    if (kb < 3) {
#pragma unroll
      for (int fa = 0; fa < 4; ++fa)
        aR[(kb + 1) & 1][fa] = *(const longx2*)(aLane + fa * 4096 + (kb + 1) * 64);
      STAGEB((kb & 1) ^ 1, kb + 1);   // issue next-tile B loads before compute
    }
    longx2 bg[4];                      // one b128 = both K=32 slices
#pragma unroll
    for (int fb = 0; fb < 4; ++fb)
      bg[fb] = *(const longx2*)(bptr + bo + fb * 1024);
    __builtin_amdgcn_s_setprio(1);
#pragma unroll
    for (int fa = 0; fa < 4; ++fa) {
#pragma unroll
      for (int fb = 0; fb < 4; ++fb)
        acc[fa][fb] = __builtin_amdgcn_mfma_f32_16x16x32_fp8_fp8(aR[kb & 1][fa].x, bg[fb].x, acc[fa][fb], 0, 0, 0);
#pragma unroll
      for (int fb = 0; fb < 4; ++fb)
        acc[fa][fb] = __builtin_amdgcn_mfma_f32_16x16x32_fp8_fp8(aR[kb & 1][fa].y, bg[fb].y, acc[fa][fb], 0, 0, 0);
    }
    __builtin_amdgcn_s_setprio(0);
    if (kb < 3) __syncthreads();   // kb3: no LDS reuse below (red is in bufs[0], reads ended kb2)
  }

  // ---- epilogue: packed-key dual argmax (u32: [31:13]=bits(acc+512), [12:0]=8191-t) ----
  const float rf = (float)relax[0];
  float jx[4], jy[4];
#pragma unroll
  for (int fb = 0; fb < 4; ++fb) {
    const float2 jj = sm.jc2[wc * 64 + fb * 16 + l15];
    jx[fb] = jj.x; jy[fb] = jj.y;
  }
  unsigned int kA[4] = {0u, 0u, 0u, 0u}, kI[4] = {0u, 0u, 0u, 0u};
  const unsigned int tinv0 = (unsigned int)(8191 - tbase);

#define EPILOG(TAIL) \
  _Pragma("unroll") for (int fa = 0; fa < 4; ++fa) { \
    _Pragma("unroll") for (int i = 0; i < 4; ++i) { \
      const int tl = wr * 64 + fa * 16 + h * 4 + i; \
      const float2 tj = sm.tc2[tl]; \
      const unsigned int tinv = tinv0 - tl; \
      _Pragma("unroll") for (int fb = 0; fb < 4; ++fb) { \
        unsigned int key = (__float_as_uint(acc[fa][fb][i] + 512.f) & 0xFFFFE000u) | tinv; \
        if (TAIL && (tbase + tl >= NP)) key = 0u; \
        if (key > kA[fb]) kA[fb] = key; \
        const float mm = fmaxf(fabsf(tj.x - jx[fb]), fabsf(tj.y - jy[fb])); \
        const unsigned int keyI = (mm <= rf) ? 0u : key; \
        if (keyI > kI[fb]) kI[fb] = keyI; \
      } \
    } \
  }

  if (tbase + BT <= NP) { EPILOG(false) } else { EPILOG(true) }
#undef EPILOG

  // reduce over the 4 h-groups (disjoint t subsets, same j); red aliases bufs[0]
  uint2* red = (uint2*)sm.bufs[0];   // [2][128]; safe: bufs[0] reads ended at kb=2 barrier
#pragma unroll
  for (int fb = 0; fb < 4; ++fb) {
#pragma unroll
    for (int d = 16; d < 64; d <<= 1) {
      const unsigned int oA = __shfl_xor(kA[fb], d);
      const unsigned int oI = __shfl_xor(kI[fb], d);
      if (oA > kA[fb]) kA[fb] = oA;
      if (oI > kI[fb]) kI[fb] = oI;
    }
    if (h == 0) red[wr * 128 + wc * 64 + fb * 16 + l15] = make_uint2(kA[fb], kI[fb]);
  }
  __syncthreads();
  if (tid < 128) {
    const int jg = jbase + tid;
    if (jg < NP) {
      uint2 p0 = red[tid];
      const uint2 p1 = red[128 + tid];
      if (p1.x > p0.x) p0.x = p1.x;
      if (p1.y > p0.y) p0.y = p1.y;
      partial[((size_t)b * NP + jg) * NTT + tt] = p0;
    }
  }
#undef STAGEB
}

// ---------------- fused combine + per-point loss + recall (wave per point) ----------------
__global__ __launch_bounds__(256)
void k_loss(const unsigned short* __restrict__ refB, const unsigned short* __restrict__ tarB,
            const float* __restrict__ un, const uint2* __restrict__ partial,
            float* __restrict__ loss_arr, float* __restrict__ rec_arr) {
  const int w = threadIdx.x >> 6, lane = threadIdx.x & 63;
  const int n = blockIdx.x * 4 + w;
  const int b = blockIdx.y;
  const int bn = b * NP + n;
  unsigned int kA = 0u, kI = 0u;
  if (lane < NTT) {
    const uint2 p = partial[(size_t)bn * NTT + lane];
    kA = p.x; kI = p.y;
  }
#pragma unroll
  for (int d = 1; d < 64; d <<= 1) {
    const unsigned int oA = __shfl_xor(kA, d);
    const unsigned int oI = __shfl_xor(kI, d);
    if (oA > kA) kA = oA;
    if (oI > kI) kI = oI;
  }
  const int nn  = 8191 - (int)(kA & 0x1FFFu);
  const int neg = 8191 - (int)(kI & 0x1FFFu);
  const ushort4 rv = *(const ushort4*)(refB + ((size_t)b * NPAD + n) * CDIM + lane * 4);
  const ushort4 tv = *(const ushort4*)(tarB + ((size_t)b * NPAD + n) * CDIM + lane * 4);
  const ushort4 gv = *(const ushort4*)(tarB + ((size_t)b * NPAD + neg) * CDIM + lane * 4);
  float dp = 0.f, dn = 0.f, d;
  d = bf2f(rv.x) - bf2f(tv.x) + 1e-6f; dp += d * d;
  d = bf2f(rv.y) - bf2f(tv.y) + 1e-6f; dp += d * d;
  d = bf2f(rv.z) - bf2f(tv.z) + 1e-6f; dp += d * d;
  d = bf2f(rv.w) - bf2f(tv.w) + 1e-6f; dp += d * d;
  d = bf2f(rv.x) - bf2f(gv.x) + 1e-6f; dn += d * d;
  d = bf2f(rv.y) - bf2f(gv.y) + 1e-6f; dn += d * d;
  d = bf2f(rv.z) - bf2f(gv.z) + 1e-6f; dn += d * d;
  d = bf2f(rv.w) - bf2f(gv.w) + 1e-6f; dn += d * d;
#pragma unroll
  for (int off = 1; off < 64; off <<= 1) {
    dp += __shfl_xor(dp, off);
    dn += __shfl_xor(dn, off);
  }
  if (lane == 0) {
    const float loss = fmaxf(sqrtf(dp) - sqrtf(dn) + 0.2f, 0.f);
    const float* unb = un + (size_t)b * 2 * NP;
    const float rec = (unb[nn] == unb[n] && unb[NP + nn] == unb[NP + n]) ? 1.f : 0.f;
    loss_arr[bn] = loss;
    rec_arr[bn] = rec;
  }
}

// ---------------- final deterministic reduce ----------------
__global__ __launch_bounds__(256)
void k_finalize(const float* __restrict__ loss_arr, const float* __restrict__ rec_arr,
                float* __restrict__ out) {
  __shared__ float l[256], rr[256];
  float ls = 0.f, rs = 0.f;
  for (int i = threadIdx.x; i < BQ * NP; i += 256) { ls += loss_arr[i]; rs += rec_arr[i]; }
  l[threadIdx.x] = ls;
  rr[threadIdx.x] = rs;
  __syncthreads();
  for (int s = 128; s > 0; s >>= 1) {
    if (threadIdx.x < s) { l[threadIdx.x] += l[threadIdx.x + s]; rr[threadIdx.x] += rr[threadIdx.x + s]; }
    __syncthreads();
  }
  if (threadIdx.x == 0) {
    out[0] = l[0] / (float)(BQ * NP);
    out[1] = rr[0] / (float)(BQ * NP);
  }
}

extern "C" void kernel_launch(void* const* d_in, const int* in_sizes, int n_in,
                              void* d_out, int out_size, void* d_ws, size_t ws_size,
                              hipStream_t stream) {
  const float* src  = (const float*)d_in[0];
  const float* tgt  = (const float*)d_in[1];
  const float* spts = (const float*)d_in[2];
  const float* tpts = (const float*)d_in[3];
  const float* un   = (const float*)d_in[4];
  const int* relax  = (const int*)d_in[5];

  char* ws = (char*)d_ws;
  unsigned short* desT     = (unsigned short*)(ws + WS_DEST);
  uint2*          partial  = (uint2*)(ws + WS_PART);   // aliases desT (dead by then)
  unsigned short* refB     = (unsigned short*)(ws + WS_REFB);
  unsigned short* tarB     = (unsigned short*)(ws + WS_TARB);
  unsigned char*  refQ     = (unsigned char*)(ws + WS_REFQ);
  unsigned char*  tarQ     = (unsigned char*)(ws + WS_TARQ);
  float*          loss_arr = (float*)(ws + WS_LOSS);
  float*          rec_arr  = (float*)(ws + WS_REC);
  float*          out      = (float*)d_out;

  k_transpose<<<dim3(NP / 32, CDIM / 64, 8), dim3(32, 8), 0, stream>>>(src, tgt, desT);
  k_sample<<<dim3(NPAD / 4, BQ, 2), 256, 0, stream>>>(desT, spts, tpts, refB, tarB, refQ, tarQ);
  k_mfma_argmax<<<NBLK, 256, 0, stream>>>(tarQ, refQ, un, relax, partial);
  k_loss<<<dim3(NP / 4, BQ), 256, 0, stream>>>(refB, tarB, un, partial, loss_arr, rec_arr);
  k_finalize<<<1, 256, 0, stream>>>(loss_arr, rec_arr, out);
}

// Round 12
// 108.156 us; speedup vs baseline: 1.1066x; 1.1066x over previous
//
#include <hip/hip_runtime.h>
#include <cstdint>
#include <cstddef>

// Problem constants: B=4, C=256, H=60, W=80, N=4800
#define BQ 4
#define CDIM 256
#define HH 60
#define WW 80
#define NP 4800
#define NPAD 4864          // 38*128
#define BT 128             // tile rows (t, A = tar)
#define BJ 128             // tile cols (j, B = ref)
#define NTT 38             // t tiles (128)
#define NTJ 38             // j tiles (128)
#define NBLK (BQ * NTJ * NTT)   // 5776, %8==0

typedef float f32x4 __attribute__((ext_vector_type(4)));
typedef unsigned short u16x8 __attribute__((ext_vector_type(8)));
typedef long longx2 __attribute__((ext_vector_type(2)));

// ---------------- ws layout (bytes) ----------------
#define WS_DEST 0              // bf16 2*4*4800*256*2 = 19,660,800 (dead after k_sample)
#define WS_PART 0              // uint2 4*4800*38*8 = 5,836,800 (aliases desT)
#define WS_REFB 19660800       // bf16 4*4864*256*2 = 9,961,472 (for k_loss)
#define WS_TARB 29622272       // bf16                9,961,472
#define WS_REFQ 39583744       // fp8 4*4864*256 = 4,980,736 (for GEMM, k-permuted)
#define WS_TARQ 44564480       // fp8                4,980,736
#define WS_LOSS 49545216       // f32 19200 = 76,800
#define WS_REC  49622016       // f32 19200
// end 49,698,816

#define GLD16(dst, src) __builtin_amdgcn_global_load_lds( \
    (const __attribute__((address_space(1))) void*)(src), \
    (__attribute__((address_space(3))) void*)(dst), 16, 0, 0)

__device__ inline unsigned short f2bf(float f) {
  unsigned int u = __float_as_uint(f);
  return (unsigned short)((u + 0x7FFFu + ((u >> 16) & 1u)) >> 16);  // RNE
}
__device__ inline float bf2f(unsigned short s) {
  return __uint_as_float((unsigned int)s << 16);
}
// f32 -> OCP e4m3fn, RNE, clamp to +-448, subnormals handled
__device__ inline unsigned char f2e4m3(float x) {
  float ax = fminf(fabsf(x), 448.f);
  const unsigned int sign = (__float_as_uint(x) >> 24) & 0x80u;
  if (ax < 0.015625f) {                     // below 2^-6: subnormal (or carry to 0x08)
    const int M = (int)rintf(ax * 512.f);   // 0..8; 8 == 2^-6 encodes as E=1,M=0
    return (unsigned char)(sign | (unsigned int)M);
  }
  unsigned int u = __float_as_uint(ax);
  u += 0x7FFFFu + ((u >> 20) & 1u);         // RNE at mantissa bit 20 (carry ok)
  unsigned int e = (u >> 23) - 120u;        // exp bias 127 -> 7
  unsigned int m = (u >> 20) & 7u;
  if (e >= 16u) { e = 15u; m = 6u; }        // clamp to 448 (rounding overshoot)
  return (unsigned char)(sign | (e << 3) | m);
}

// ---------------- transpose des (C, HW) f32 -> (HW, C) bf16 ----------------
__global__ __launch_bounds__(256)
void k_transpose(const float* __restrict__ src, const float* __restrict__ tgt,
                 unsigned short* __restrict__ desT) {
  __shared__ float tile[64][33];
  const int z = blockIdx.z;  // tensor*4 + b
  const float* in = ((z >> 2) ? tgt : src) + (size_t)(z & 3) * CDIM * NP;
  unsigned short* out = desT + (size_t)z * NP * CDIM;
  const int hw0 = blockIdx.x * 32;
  const int c0 = blockIdx.y * 64;
  const int tx = threadIdx.x, ty = threadIdx.y;
#pragma unroll
  for (int q = 0; q < 8; ++q)
    tile[ty + q * 8][tx] = in[(size_t)(c0 + ty + q * 8) * NP + hw0 + tx];
  __syncthreads();
  const int lt = ty * 32 + tx;
  const int c2 = lt & 7;        // 8 channels each
  const int hw = lt >> 3;       // 0..31
  u16x8 o;
#pragma unroll
  for (int k = 0; k < 8; ++k) o[k] = f2bf(tile[c2 * 8 + k][hw]);
  *(u16x8*)(out + (size_t)(hw0 + hw) * CDIM + c0 + c2 * 8) = o;
}

// ---------------- bilinear sample + L2 normalize -> bf16 rows + k-permuted fp8 rows ----------------
// fp8 rows store byte (kb*64 + ks*32 + h*8 + b) at position (kb*64 + h*16 + ks*8 + b):
// a single ds_read_b128 at slot h then yields both K=32 MFMA slices (low/high 8 B).
// Same permutation on ref and tar -> dot products unchanged.
__global__ __launch_bounds__(256)
void k_sample(const unsigned short* __restrict__ desT,
              const float* __restrict__ spts, const float* __restrict__ tpts,
              unsigned short* __restrict__ refB, unsigned short* __restrict__ tarB,
              unsigned char* __restrict__ refQ, unsigned char* __restrict__ tarQ) {
  const int w = threadIdx.x >> 6, lane = threadIdx.x & 63;
  const int n = blockIdx.x * 4 + w;         // 0..NPAD-1
  const int b = blockIdx.y;
  const int tensor = blockIdx.z;            // 0: ref, 1: tar
  unsigned short* outRowB = (tensor ? tarB : refB) + ((size_t)b * NPAD + n) * CDIM;
  unsigned char*  outRowQ = (tensor ? tarQ : refQ) + ((size_t)b * NPAD + n) * CDIM;
  const int c0 = lane * 4;
  // permuted uchar4 position (bits: kb[7:6] | h[4:3]->[5:4] | ks[5]->[3] | b[2:0])
  const int dstq = (c0 & 0xC0) | ((c0 & 24) << 1) | ((c0 & 32) >> 2) | (c0 & 7);
  if (n >= NP) {  // zero pad rows (uniform per wave)
    *(ushort4*)(outRowB + c0) = make_ushort4(0, 0, 0, 0);
    *(uchar4*)(outRowQ + dstq) = make_uchar4(0, 0, 0, 0);
    return;
  }
  const float* pts = (tensor ? tpts : spts) + ((size_t)b * NP + n) * 2;
  const float gx = pts[0], gy = pts[1];
  const float x = (gx + 1.f) * ((WW - 1) * 0.5f);
  const float y = (gy + 1.f) * ((HH - 1) * 0.5f);
  float x0f = fminf(fmaxf(floorf(x), 0.f), (float)(WW - 1));
  float y0f = fminf(fmaxf(floorf(y), 0.f), (float)(HH - 1));
  float x1f = fminf(x0f + 1.f, (float)(WW - 1));
  float y1f = fminf(y0f + 1.f, (float)(HH - 1));
  const float wx = x - x0f, wy = y - y0f;
  const int ix0 = (int)x0f, ix1 = (int)x1f, iy0 = (int)y0f, iy1 = (int)y1f;
  const unsigned short* base = desT + (size_t)(tensor * 4 + b) * NP * CDIM + c0;
  const ushort4 u00 = *(const ushort4*)(base + (size_t)(iy0 * WW + ix0) * CDIM);
  const ushort4 u01 = *(const ushort4*)(base + (size_t)(iy0 * WW + ix1) * CDIM);
  const ushort4 u10 = *(const ushort4*)(base + (size_t)(iy1 * WW + ix0) * CDIM);
  const ushort4 u11 = *(const ushort4*)(base + (size_t)(iy1 * WW + ix1) * CDIM);
  const float w00 = (1.f - wx) * (1.f - wy), w01 = wx * (1.f - wy);
  const float w10 = (1.f - wx) * wy,         w11 = wx * wy;
  float4 v;
  v.x = bf2f(u00.x) * w00 + bf2f(u01.x) * w01 + bf2f(u10.x) * w10 + bf2f(u11.x) * w11;
  v.y = bf2f(u00.y) * w00 + bf2f(u01.y) * w01 + bf2f(u10.y) * w10 + bf2f(u11.y) * w11;
  v.z = bf2f(u00.z) * w00 + bf2f(u01.z) * w01 + bf2f(u10.z) * w10 + bf2f(u11.z) * w11;
  v.w = bf2f(u00.w) * w00 + bf2f(u01.w) * w01 + bf2f(u10.w) * w10 + bf2f(u11.w) * w11;
  float s0 = v.x + 1e-8f, s1 = v.y + 1e-8f, s2 = v.z + 1e-8f, s3 = v.w + 1e-8f;
  float sum = s0 * s0 + s1 * s1 + s2 * s2 + s3 * s3;
#pragma unroll
  for (int d = 1; d < 64; d <<= 1) sum += __shfl_xor(sum, d);
  const float inv = 1.f / (sqrtf(sum) + 1e-8f);
  *(ushort4*)(outRowB + c0) =
      make_ushort4(f2bf(v.x * inv), f2bf(v.y * inv), f2bf(v.z * inv), f2bf(v.w * inv));
  const float invq = inv * 16.f;   // scale into e4m3 normal range; dot' = 256*dot
  *(uchar4*)(outRowQ + dstq) =
      make_uchar4(f2e4m3(v.x * invq), f2e4m3(v.y * invq), f2e4m3(v.z * invq), f2e4m3(v.w * invq));
}

// ---------------- fp8 MFMA GEMM (128t x 128j, BK=64) + fused dual argmax ----------------
// Round-10 structure (proven 49.5 us) restored verbatim: BOTH operands via
// global_load_lds staging (round-11's A-to-register variant exposed VMEM latency at
// the vmcnt(0) barrier drain and lost a resident block: 67 us). Single delta vs
// round 10: T5 s_setprio around the MFMA cluster (4 independent blocks/CU = the
// phase-diverse case where setprio pays; zero register/LDS cost).
// LDS rows 64 B, zero-conflict swizzle (store slot s^((row>>1)&3), round-5 proven).
// One ds_read_b128 per fragment per kb covers both K=32 slices (k-permuted fp8 rows).
// red[] aliases bufs[0] after its last reads (kb=2 barrier). VGPR 60 + 64 AGPR = 124
// at (256,4): exactly fits 4 waves/SIMD x 124 <= 512 — do not add register pressure.
struct Smem {
  char bufs[2][16384];   // per buf: A [128][64B] @0, B [128][64B] @8192
  float2 tc2[128];       // t coords (x,y)
  float2 jc2[128];       // j coords (x,y)
};                       // 34,816 B -> 4 blocks/CU

__global__ __launch_bounds__(256, 4)
void k_mfma_argmax(const unsigned char* __restrict__ tarQ,
                   const unsigned char* __restrict__ refQ,
                   const float* __restrict__ un, const int* __restrict__ relax,
                   uint2* __restrict__ partial) {
  __shared__ Smem sm;
  const int tid = threadIdx.x;
  const int lane = tid & 63;
  const int wid = tid >> 6;

  // XCD swizzle (5776 % 8 == 0)
  const int bid = blockIdx.x;
  const int item = (bid & 7) * (NBLK / 8) + (bid >> 3);
  const int b = item / (NTJ * NTT);
  const int r2 = item - b * (NTJ * NTT);
  const int jt = r2 / NTT, tt = r2 % NTT;
  const int tbase = tt * BT, jbase = jt * BJ;
  const float* unb = un + (size_t)b * 2 * NP;

  // stage coords into LDS (before first barrier)
  if (tid < 128) {
    const int tg = (tbase + tid < NP) ? tbase + tid : NP - 1;
    sm.tc2[tid] = make_float2(unb[tg], unb[NP + tg]);
  } else {
    const int i2 = tid - 128;
    const int jg = (jbase + i2 < NP) ? jbase + i2 : NP - 1;
    sm.jc2[i2] = make_float2(unb[jg], unb[NP + jg]);
  }

  // staging: waves 0-1 -> A (64 rows each), waves 2-3 -> B (64 rows each)
  // global rows are 256 B (fp8, k-permuted); kb selects a 64-B slice. Source slot pre-swizzled.
  const char* aSrc = (const char*)(tarQ + ((size_t)b * NPAD + tbase) * CDIM);
  const char* bSrc = (const char*)(refQ + ((size_t)b * NPAD + jbase) * CDIM);
  const int srcSlot = ((lane & 3) ^ ((lane >> 3) & 3)) * 16;
  const char* gl; int ldsOff;
  if (wid < 2) {
    gl = aSrc + (size_t)(wid * 64 + (lane >> 2)) * 256 + srcSlot;
    ldsOff = wid * 4096;
  } else {
    gl = bSrc + (size_t)((wid - 2) * 64 + (lane >> 2)) * 256 + srcSlot;
    ldsOff = 8192 + (wid - 2) * 4096;
  }

#define STAGE(buf, kb) do { \
    char* ldst = sm.bufs[buf] + ldsOff; \
    const char* gsp = gl + (kb) * 64; \
    _Pragma("unroll") for (int qq = 0; qq < 4; ++qq) \
      GLD16(ldst + qq * 1024, gsp + (size_t)qq * 4096); \
  } while (0)

  const int wr = wid >> 1, wc = wid & 1;   // wave tile: 64t x 64j
  const int l15 = lane & 15, h = lane >> 4;
  const int sx = (h ^ ((l15 >> 1) & 3)) << 4;   // swizzled 16-B slot (round-5 pattern)

  f32x4 acc[4][4];
#pragma unroll
  for (int fa = 0; fa < 4; ++fa)
#pragma unroll
    for (int fb = 0; fb < 4; ++fb) acc[fa][fb] = (f32x4){0.f, 0.f, 0.f, 0.f};

  // loop-invariant LDS read bases: fragment reads are base + imm offset
  const char* aptr = sm.bufs[0] + (wr * 64 + l15) * 64 + sx;
  const char* bptr = sm.bufs[0] + 8192 + (wc * 64 + l15) * 64 + sx;

  STAGE(0, 0);
  __syncthreads();
#pragma unroll
  for (int kb = 0; kb < 4; ++kb) {   // K = 256 = 4 * 64
    const int bo = (kb & 1) * 16384;
    if (kb < 3) STAGE((kb & 1) ^ 1, kb + 1);   // issue next-tile loads before compute
    longx2 bg[4];                               // one b128 = both K=32 slices
#pragma unroll
    for (int fb = 0; fb < 4; ++fb)
      bg[fb] = *(const longx2*)(bptr + bo + fb * 1024);
    __builtin_amdgcn_s_setprio(1);
#pragma unroll
    for (int fa = 0; fa < 4; ++fa) {
      const longx2 af = *(const longx2*)(aptr + bo + fa * 1024);
#pragma unroll
      for (int fb = 0; fb < 4; ++fb)
        acc[fa][fb] = __builtin_amdgcn_mfma_f32_16x16x32_fp8_fp8(af.x, bg[fb].x, acc[fa][fb], 0, 0, 0);
#pragma unroll
      for (int fb = 0; fb < 4; ++fb)
        acc[fa][fb] = __builtin_amdgcn_mfma_f32_16x16x32_fp8_fp8(af.y, bg[fb].y, acc[fa][fb], 0, 0, 0);
    }
    __builtin_amdgcn_s_setprio(0);
    if (kb < 3) __syncthreads();   // kb3: no LDS reuse below (red is in bufs[0], reads ended kb2)
  }

  // ---- epilogue: packed-key dual argmax (u32: [31:13]=bits(acc+512), [12:0]=8191-t) ----
  const float rf = (float)relax[0];
  float jx[4], jy[4];
#pragma unroll
  for (int fb = 0; fb < 4; ++fb) {
    const float2 jj = sm.jc2[wc * 64 + fb * 16 + l15];
    jx[fb] = jj.x; jy[fb] = jj.y;
  }
  unsigned int kA[4] = {0u, 0u, 0u, 0u}, kI[4] = {0u, 0u, 0u, 0u};
  const unsigned int tinv0 = (unsigned int)(8191 - tbase);

#define EPILOG(TAIL) \
  _Pragma("unroll") for (int fa = 0; fa < 4; ++fa) { \
    _Pragma("unroll") for (int i = 0; i < 4; ++i) { \
      const int tl = wr * 64 + fa * 16 + h * 4 + i; \
      const float2 tj = sm.tc2[tl]; \
      const unsigned int tinv = tinv0 - tl; \
      _Pragma("unroll") for (int fb = 0; fb < 4; ++fb) { \
        unsigned int key = (__float_as_uint(acc[fa][fb][i] + 512.f) & 0xFFFFE000u) | tinv; \
        if (TAIL && (tbase + tl >= NP)) key = 0u; \
        if (key > kA[fb]) kA[fb] = key; \
        const float mm = fmaxf(fabsf(tj.x - jx[fb]), fabsf(tj.y - jy[fb])); \
        const unsigned int keyI = (mm <= rf) ? 0u : key; \
        if (keyI > kI[fb]) kI[fb] = keyI; \
      } \
    } \
  }

  if (tbase + BT <= NP) { EPILOG(false) } else { EPILOG(true) }
#undef EPILOG

  // reduce over the 4 h-groups (disjoint t subsets, same j); red aliases bufs[0]
  uint2* red = (uint2*)sm.bufs[0];   // [2][128]; safe: bufs[0] reads ended at kb=2 barrier
#pragma unroll
  for (int fb = 0; fb < 4; ++fb) {
#pragma unroll
    for (int d = 16; d < 64; d <<= 1) {
      const unsigned int oA = __shfl_xor(kA[fb], d);
      const unsigned int oI = __shfl_xor(kI[fb], d);
      if (oA > kA[fb]) kA[fb] = oA;
      if (oI > kI[fb]) kI[fb] = oI;
    }
    if (h == 0) red[wr * 128 + wc * 64 + fb * 16 + l15] = make_uint2(kA[fb], kI[fb]);
  }
  __syncthreads();
  if (tid < 128) {
    const int jg = jbase + tid;
    if (jg < NP) {
      uint2 p0 = red[tid];
      const uint2 p1 = red[128 + tid];
      if (p1.x > p0.x) p0.x = p1.x;
      if (p1.y > p0.y) p0.y = p1.y;
      partial[((size_t)b * NP + jg) * NTT + tt] = p0;
    }
  }
#undef STAGE
}

// ---------------- fused combine + per-point loss + recall (wave per point) ----------------
__global__ __launch_bounds__(256)
void k_loss(const unsigned short* __restrict__ refB, const unsigned short* __restrict__ tarB,
            const float* __restrict__ un, const uint2* __restrict__ partial,
            float* __restrict__ loss_arr, float* __restrict__ rec_arr) {
  const int w = threadIdx.x >> 6, lane = threadIdx.x & 63;
  const int n = blockIdx.x * 4 + w;
  const int b = blockIdx.y;
  const int bn = b * NP + n;
  unsigned int kA = 0u, kI = 0u;
  if (lane < NTT) {
    const uint2 p = partial[(size_t)bn * NTT + lane];
    kA = p.x; kI = p.y;
  }
#pragma unroll
  for (int d = 1; d < 64; d <<= 1) {
    const unsigned int oA = __shfl_xor(kA, d);
    const unsigned int oI = __shfl_xor(kI, d);
    if (oA > kA) kA = oA;
    if (oI > kI) kI = oI;
  }
  const int nn  = 8191 - (int)(kA & 0x1FFFu);
  const int neg = 8191 - (int)(kI & 0x1FFFu);
  const ushort4 rv = *(const ushort4*)(refB + ((size_t)b * NPAD + n) * CDIM + lane * 4);
  const ushort4 tv = *(const ushort4*)(tarB + ((size_t)b * NPAD + n) * CDIM + lane * 4);
  const ushort4 gv = *(const ushort4*)(tarB + ((size_t)b * NPAD + neg) * CDIM + lane * 4);
  float dp = 0.f, dn = 0.f, d;
  d = bf2f(rv.x) - bf2f(tv.x) + 1e-6f; dp += d * d;
  d = bf2f(rv.y) - bf2f(tv.y) + 1e-6f; dp += d * d;
  d = bf2f(rv.z) - bf2f(tv.z) + 1e-6f; dp += d * d;
  d = bf2f(rv.w) - bf2f(tv.w) + 1e-6f; dp += d * d;
  d = bf2f(rv.x) - bf2f(gv.x) + 1e-6f; dn += d * d;
  d = bf2f(rv.y) - bf2f(gv.y) + 1e-6f; dn += d * d;
  d = bf2f(rv.z) - bf2f(gv.z) + 1e-6f; dn += d * d;
  d = bf2f(rv.w) - bf2f(gv.w) + 1e-6f; dn += d * d;
#pragma unroll
  for (int off = 1; off < 64; off <<= 1) {
    dp += __shfl_xor(dp, off);
    dn += __shfl_xor(dn, off);
  }
  if (lane == 0) {
    const float loss = fmaxf(sqrtf(dp) - sqrtf(dn) + 0.2f, 0.f);
    const float* unb = un + (size_t)b * 2 * NP;
    const float rec = (unb[nn] == unb[n] && unb[NP + nn] == unb[NP + n]) ? 1.f : 0.f;
    loss_arr[bn] = loss;
    rec_arr[bn] = rec;
  }
}

// ---------------- final deterministic reduce ----------------
__global__ __launch_bounds__(256)
void k_finalize(const float* __restrict__ loss_arr, const float* __restrict__ rec_arr,
                float* __restrict__ out) {
  __shared__ float l[256], rr[256];
  float ls = 0.f, rs = 0.f;
  for (int i = threadIdx.x; i < BQ * NP; i += 256) { ls += loss_arr[i]; rs += rec_arr[i]; }
  l[threadIdx.x] = ls;
  rr[threadIdx.x] = rs;
  __syncthreads();
  for (int s = 128; s > 0; s >>= 1) {
    if (threadIdx.x < s) { l[threadIdx.x] += l[threadIdx.x + s]; rr[threadIdx.x] += rr[threadIdx.x + s]; }
    __syncthreads();
  }
  if (threadIdx.x == 0) {
    out[0] = l[0] / (float)(BQ * NP);
    out[1] = rr[0] / (float)(BQ * NP);
  }
}

extern "C" void kernel_launch(void* const* d_in, const int* in_sizes, int n_in,
                              void* d_out, int out_size, void* d_ws, size_t ws_size,
                              hipStream_t stream) {
  const float* src  = (const float*)d_in[0];
  const float* tgt  = (const float*)d_in[1];
  const float* spts = (const float*)d_in[2];
  const float* tpts = (const float*)d_in[3];
  const float* un   = (const float*)d_in[4];
  const int* relax  = (const int*)d_in[5];

  char* ws = (char*)d_ws;
  unsigned short* desT     = (unsigned short*)(ws + WS_DEST);
  uint2*          partial  = (uint2*)(ws + WS_PART);   // aliases desT (dead by then)
  unsigned short* refB     = (unsigned short*)(ws + WS_REFB);
  unsigned short* tarB     = (unsigned short*)(ws + WS_TARB);
  unsigned char*  refQ     = (unsigned char*)(ws + WS_REFQ);
  unsigned char*  tarQ     = (unsigned char*)(ws + WS_TARQ);
  float*          loss_arr = (float*)(ws + WS_LOSS);
  float*          rec_arr  = (float*)(ws + WS_REC);
  float*          out      = (float*)d_out;

  k_transpose<<<dim3(NP / 32, CDIM / 64, 8), dim3(32, 8), 0, stream>>>(src, tgt, desT);
  k_sample<<<dim3(NPAD / 4, BQ, 2), 256, 0, stream>>>(desT, spts, tpts, refB, tarB, refQ, tarQ);
  k_mfma_argmax<<<NBLK, 256, 0, stream>>>(tarQ, refQ, un, relax, partial);
  k_loss<<<dim3(NP / 4, BQ), 256, 0, stream>>>(refB, tarB, un, partial, loss_arr, rec_arr);
  k_finalize<<<1, 256, 0, stream>>>(loss_arr, rec_arr, out);
}

// Round 13
// 105.408 us; speedup vs baseline: 1.1355x; 1.0261x over previous
//
#include <hip/hip_runtime.h>
#include <cstdint>
#include <cstddef>

// Problem constants: B=4, C=256, H=60, W=80, N=4800
#define BQ 4
#define CDIM 256
#define HH 60
#define WW 80
#define NP 4800
#define NPAD 4864          // 38*128
#define BT 128             // tile rows (t, A = tar)
#define BJ 128             // tile cols (j, B = ref)
#define NTT 38             // t tiles (128)
#define NTJ 38             // j tiles (128)
#define NBLK (BQ * NTJ * NTT)   // 5776, %8==0

typedef float f32x4 __attribute__((ext_vector_type(4)));
typedef float f32x16 __attribute__((ext_vector_type(16)));
typedef int i32x4 __attribute__((ext_vector_type(4)));
typedef int i32x8 __attribute__((ext_vector_type(8)));
typedef unsigned short u16x8 __attribute__((ext_vector_type(8)));

// ---------------- ws layout (bytes) ----------------
#define WS_DEST 0              // bf16 2*4*4800*256*2 = 19,660,800 (dead after k_sample)
#define WS_PART 0              // uint2 4*4800*38*8 = 5,836,800 (aliases desT)
#define WS_REFB 19660800       // bf16 4*4864*256*2 = 9,961,472 (for k_loss)
#define WS_TARB 29622272       // bf16                9,961,472
#define WS_REFQ 39583744       // fp8 4*4864*256 = 4,980,736 (for GEMM, plain k layout)
#define WS_TARQ 44564480       // fp8                4,980,736
#define WS_LOSS 49545216       // f32 19200 = 76,800
#define WS_REC  49622016       // f32 19200
// end 49,698,816

#define GLD16(dst, src) __builtin_amdgcn_global_load_lds( \
    (const __attribute__((address_space(1))) void*)(src), \
    (__attribute__((address_space(3))) void*)(dst), 16, 0, 0)

__device__ inline unsigned short f2bf(float f) {
  unsigned int u = __float_as_uint(f);
  return (unsigned short)((u + 0x7FFFu + ((u >> 16) & 1u)) >> 16);  // RNE
}
__device__ inline float bf2f(unsigned short s) {
  return __uint_as_float((unsigned int)s << 16);
}
// f32 -> OCP e4m3fn, RNE, clamp to +-448, subnormals handled
__device__ inline unsigned char f2e4m3(float x) {
  float ax = fminf(fabsf(x), 448.f);
  const unsigned int sign = (__float_as_uint(x) >> 24) & 0x80u;
  if (ax < 0.015625f) {                     // below 2^-6: subnormal (or carry to 0x08)
    const int M = (int)rintf(ax * 512.f);   // 0..8; 8 == 2^-6 encodes as E=1,M=0
    return (unsigned char)(sign | (unsigned int)M);
  }
  unsigned int u = __float_as_uint(ax);
  u += 0x7FFFFu + ((u >> 20) & 1u);         // RNE at mantissa bit 20 (carry ok)
  unsigned int e = (u >> 23) - 120u;        // exp bias 127 -> 7
  unsigned int m = (u >> 20) & 7u;
  if (e >= 16u) { e = 15u; m = 6u; }        // clamp to 448 (rounding overshoot)
  return (unsigned char)(sign | (e << 3) | m);
}

// ---------------- transpose des (C, HW) f32 -> (HW, C) bf16 ----------------
__global__ __launch_bounds__(256)
void k_transpose(const float* __restrict__ src, const float* __restrict__ tgt,
                 unsigned short* __restrict__ desT) {
  __shared__ float tile[64][33];
  const int z = blockIdx.z;  // tensor*4 + b
  const float* in = ((z >> 2) ? tgt : src) + (size_t)(z & 3) * CDIM * NP;
  unsigned short* out = desT + (size_t)z * NP * CDIM;
  const int hw0 = blockIdx.x * 32;
  const int c0 = blockIdx.y * 64;
  const int tx = threadIdx.x, ty = threadIdx.y;
#pragma unroll
  for (int q = 0; q < 8; ++q)
    tile[ty + q * 8][tx] = in[(size_t)(c0 + ty + q * 8) * NP + hw0 + tx];
  __syncthreads();
  const int lt = ty * 32 + tx;
  const int c2 = lt & 7;        // 8 channels each
  const int hw = lt >> 3;       // 0..31
  u16x8 o;
#pragma unroll
  for (int k = 0; k < 8; ++k) o[k] = f2bf(tile[c2 * 8 + k][hw]);
  *(u16x8*)(out + (size_t)(hw0 + hw) * CDIM + c0 + c2 * 8) = o;
}

// ---------------- bilinear sample + L2 normalize -> bf16 rows + fp8 rows (plain k) ----------------
// 32x32x64 f8f6f4 wants 32 CONSECUTIVE k per lane -> no k-permute needed (round-8's
// permute was for the 16x16x32 hi/lo split; deleted).
__global__ __launch_bounds__(256)
void k_sample(const unsigned short* __restrict__ desT,
              const float* __restrict__ spts, const float* __restrict__ tpts,
              unsigned short* __restrict__ refB, unsigned short* __restrict__ tarB,
              unsigned char* __restrict__ refQ, unsigned char* __restrict__ tarQ) {
  const int w = threadIdx.x >> 6, lane = threadIdx.x & 63;
  const int n = blockIdx.x * 4 + w;         // 0..NPAD-1
  const int b = blockIdx.y;
  const int tensor = blockIdx.z;            // 0: ref, 1: tar
  unsigned short* outRowB = (tensor ? tarB : refB) + ((size_t)b * NPAD + n) * CDIM;
  unsigned char*  outRowQ = (tensor ? tarQ : refQ) + ((size_t)b * NPAD + n) * CDIM;
  const int c0 = lane * 4;
  if (n >= NP) {  // zero pad rows (uniform per wave)
    *(ushort4*)(outRowB + c0) = make_ushort4(0, 0, 0, 0);
    *(uchar4*)(outRowQ + c0) = make_uchar4(0, 0, 0, 0);
    return;
  }
  const float* pts = (tensor ? tpts : spts) + ((size_t)b * NP + n) * 2;
  const float gx = pts[0], gy = pts[1];
  const float x = (gx + 1.f) * ((WW - 1) * 0.5f);
  const float y = (gy + 1.f) * ((HH - 1) * 0.5f);
  float x0f = fminf(fmaxf(floorf(x), 0.f), (float)(WW - 1));
  float y0f = fminf(fmaxf(floorf(y), 0.f), (float)(HH - 1));
  float x1f = fminf(x0f + 1.f, (float)(WW - 1));
  float y1f = fminf(y0f + 1.f, (float)(HH - 1));
  const float wx = x - x0f, wy = y - y0f;
  const int ix0 = (int)x0f, ix1 = (int)x1f, iy0 = (int)y0f, iy1 = (int)y1f;
  const unsigned short* base = desT + (size_t)(tensor * 4 + b) * NP * CDIM + c0;
  const ushort4 u00 = *(const ushort4*)(base + (size_t)(iy0 * WW + ix0) * CDIM);
  const ushort4 u01 = *(const ushort4*)(base + (size_t)(iy0 * WW + ix1) * CDIM);
  const ushort4 u10 = *(const ushort4*)(base + (size_t)(iy1 * WW + ix0) * CDIM);
  const ushort4 u11 = *(const ushort4*)(base + (size_t)(iy1 * WW + ix1) * CDIM);
  const float w00 = (1.f - wx) * (1.f - wy), w01 = wx * (1.f - wy);
  const float w10 = (1.f - wx) * wy,         w11 = wx * wy;
  float4 v;
  v.x = bf2f(u00.x) * w00 + bf2f(u01.x) * w01 + bf2f(u10.x) * w10 + bf2f(u11.x) * w11;
  v.y = bf2f(u00.y) * w00 + bf2f(u01.y) * w01 + bf2f(u10.y) * w10 + bf2f(u11.y) * w11;
  v.z = bf2f(u00.z) * w00 + bf2f(u01.z) * w01 + bf2f(u10.z) * w10 + bf2f(u11.z) * w11;
  v.w = bf2f(u00.w) * w00 + bf2f(u01.w) * w01 + bf2f(u10.w) * w10 + bf2f(u11.w) * w11;
  float s0 = v.x + 1e-8f, s1 = v.y + 1e-8f, s2 = v.z + 1e-8f, s3 = v.w + 1e-8f;
  float sum = s0 * s0 + s1 * s1 + s2 * s2 + s3 * s3;
#pragma unroll
  for (int d = 1; d < 64; d <<= 1) sum += __shfl_xor(sum, d);
  const float inv = 1.f / (sqrtf(sum) + 1e-8f);
  *(ushort4*)(outRowB + c0) =
      make_ushort4(f2bf(v.x * inv), f2bf(v.y * inv), f2bf(v.z * inv), f2bf(v.w * inv));
  const float invq = inv * 16.f;   // scale into e4m3 normal range; dot' = 256*dot
  *(uchar4*)(outRowQ + c0) =
      make_uchar4(f2e4m3(v.x * invq), f2e4m3(v.y * invq), f2e4m3(v.z * invq), f2e4m3(v.w * invq));
}

// ---------------- MX-fp8 MFMA GEMM (128t x 128j, 32x32x64, unit scales) + dual argmax ----------------
// Round-13 change: mfma_scale_f32_32x32x64_f8f6f4 with e8m0 scales = 1.0 (0x7F) — 2x the
// non-scaled fp8 rate (m59: 4686 TF), halving the 22 us MFMA term. Operand wants 32
// consecutive k per lane -> plain fp8 layout, staging identical to round 10 (proven
// slot-XOR swizzle: stored slot s holds original s^((row>>1)&3); lane reads slots
// (2kg+i)^((l31>>1)&3) -> 8 consecutive lanes cover all 32 banks, conflict-free).
// C/D 32x32 map (dtype-independent, m121-128): col=lane&31, row=(reg&3)+8*(reg>>2)+4*(lane>>5).
// Cross-lane t-reduce shrinks to ONE shfl_xor(32) step. red[] aliases bufs[0] (last
// read kb=2, barrier'd). VGPR budget tight (~126/128 at (256,4)): FETCH_SIZE is the
// spill tripwire. (512,6)-style oversubscription spills -> 7x regression (round-6).
struct Smem {
  char bufs[2][16384];   // per buf: A [128][64B] @0, B [128][64B] @8192
  float2 tc2[128];       // t coords (x,y)
  float2 jc2[128];       // j coords (x,y)
};                       // 34,816 B -> 4 blocks/CU

__global__ __launch_bounds__(256, 4)
void k_mfma_argmax(const unsigned char* __restrict__ tarQ,
                   const unsigned char* __restrict__ refQ,
                   const float* __restrict__ un, const int* __restrict__ relax,
                   uint2* __restrict__ partial) {
  __shared__ Smem sm;
  const int tid = threadIdx.x;
  const int lane = tid & 63;
  const int wid = tid >> 6;

  // XCD swizzle (5776 % 8 == 0)
  const int bid = blockIdx.x;
  const int item = (bid & 7) * (NBLK / 8) + (bid >> 3);
  const int b = item / (NTJ * NTT);
  const int r2 = item - b * (NTJ * NTT);
  const int jt = r2 / NTT, tt = r2 % NTT;
  const int tbase = tt * BT, jbase = jt * BJ;
  const float* unb = un + (size_t)b * 2 * NP;

  // stage coords into LDS (before first barrier)
  if (tid < 128) {
    const int tg = (tbase + tid < NP) ? tbase + tid : NP - 1;
    sm.tc2[tid] = make_float2(unb[tg], unb[NP + tg]);
  } else {
    const int i2 = tid - 128;
    const int jg = (jbase + i2 < NP) ? jbase + i2 : NP - 1;
    sm.jc2[i2] = make_float2(unb[jg], unb[NP + jg]);
  }

  // staging: waves 0-1 -> A (64 rows each), waves 2-3 -> B (64 rows each)
  // global rows are 256 B (fp8, plain k); kb selects a 64-B slice. Source slot pre-swizzled:
  // (l&3) ^ ((l>>3)&3) == slot ^ ((row>>1)&3) for row = base + (lane>>2).
  const char* aSrc = (const char*)(tarQ + ((size_t)b * NPAD + tbase) * CDIM);
  const char* bSrc = (const char*)(refQ + ((size_t)b * NPAD + jbase) * CDIM);
  const int srcSlot = ((lane & 3) ^ ((lane >> 3) & 3)) * 16;
  const char* gl; int ldsOff;
  if (wid < 2) {
    gl = aSrc + (size_t)(wid * 64 + (lane >> 2)) * 256 + srcSlot;
    ldsOff = wid * 4096;
  } else {
    gl = bSrc + (size_t)((wid - 2) * 64 + (lane >> 2)) * 256 + srcSlot;
    ldsOff = 8192 + (wid - 2) * 4096;
  }

#define STAGE(buf, kb) do { \
    char* ldst = sm.bufs[buf] + ldsOff; \
    const char* gsp = gl + (kb) * 64; \
    _Pragma("unroll") for (int qq = 0; qq < 4; ++qq) \
      GLD16(ldst + qq * 1024, gsp + (size_t)qq * 4096); \
  } while (0)

  const int wr = wid >> 1, wc = wid & 1;   // wave tile: 64t x 64j
  const int l31 = lane & 31, kg = lane >> 5;
  const int swm = (l31 >> 1) & 3;                 // read-side slot swizzle
  const int sx0 = ((2 * kg) ^ swm) << 4;
  const int sx1 = ((2 * kg + 1) ^ swm) << 4;

  f32x16 acc[2][2];
#pragma unroll
  for (int fa = 0; fa < 2; ++fa)
#pragma unroll
    for (int fb = 0; fb < 2; ++fb)
#pragma unroll
      for (int r = 0; r < 16; ++r) acc[fa][fb][r] = 0.f;

  // loop-invariant LDS read bases
  const char* aptr = sm.bufs[0] + (wr * 64 + l31) * 64;
  const char* bptr = sm.bufs[0] + 8192 + (wc * 64 + l31) * 64;

  STAGE(0, 0);
  __syncthreads();
#pragma unroll
  for (int kb = 0; kb < 4; ++kb) {   // K = 256 = 4 * 64
    const int bo = (kb & 1) * 16384;
    if (kb < 3) STAGE((kb & 1) ^ 1, kb + 1);   // issue next-tile loads before compute
    i32x8 aF[2], bF[2];
#pragma unroll
    for (int f = 0; f < 2; ++f) {
      const i32x4 alo = *(const i32x4*)(aptr + bo + f * 2048 + sx0);
      const i32x4 ahi = *(const i32x4*)(aptr + bo + f * 2048 + sx1);
      aF[f] = __builtin_shufflevector(alo, ahi, 0, 1, 2, 3, 4, 5, 6, 7);
      const i32x4 blo = *(const i32x4*)(bptr + bo + f * 2048 + sx0);
      const i32x4 bhi = *(const i32x4*)(bptr + bo + f * 2048 + sx1);
      bF[f] = __builtin_shufflevector(blo, bhi, 0, 1, 2, 3, 4, 5, 6, 7);
    }
    __builtin_amdgcn_s_setprio(1);
#pragma unroll
    for (int fa = 0; fa < 2; ++fa)
#pragma unroll
      for (int fb = 0; fb < 2; ++fb)
        acc[fa][fb] = __builtin_amdgcn_mfma_scale_f32_32x32x64_f8f6f4(
            aF[fa], bF[fb], acc[fa][fb], 0, 0,
            0, 0x7F7F7F7F, 0, 0x7F7F7F7F);   // fmt fp8/fp8, scales = 1.0
    __builtin_amdgcn_s_setprio(0);
    if (kb < 3) __syncthreads();   // kb3: no LDS reuse below (red is in bufs[0], reads ended kb2)
  }

  // ---- epilogue: packed-key dual argmax (u32: [31:13]=bits(acc+512), [12:0]=8191-t) ----
  // 32x32 C/D map: col j = wc*64 + fb*32 + l31; row t = wr*64 + fa*32 + 4*kg + (reg&3) + 8*(reg>>2)
  const float rf = (float)relax[0];
  float jx[2], jy[2];
#pragma unroll
  for (int fb = 0; fb < 2; ++fb) {
    const float2 jj = sm.jc2[wc * 64 + fb * 32 + l31];
    jx[fb] = jj.x; jy[fb] = jj.y;
  }
  unsigned int kA[2] = {0u, 0u}, kI[2] = {0u, 0u};
  const unsigned int tinv0 = (unsigned int)(8191 - tbase);

#define EPILOG(TAIL) \
  _Pragma("unroll") for (int fa = 0; fa < 2; ++fa) { \
    _Pragma("unroll") for (int reg = 0; reg < 16; ++reg) { \
      const int tl = wr * 64 + fa * 32 + 4 * kg + (reg & 3) + 8 * (reg >> 2); \
      const float2 tj = sm.tc2[tl]; \
      const unsigned int tinv = tinv0 - tl; \
      _Pragma("unroll") for (int fb = 0; fb < 2; ++fb) { \
        unsigned int key = (__float_as_uint(acc[fa][fb][reg] + 512.f) & 0xFFFFE000u) | tinv; \
        if (TAIL && (tbase + tl >= NP)) key = 0u; \
        if (key > kA[fb]) kA[fb] = key; \
        const float mm = fmaxf(fabsf(tj.x - jx[fb]), fabsf(tj.y - jy[fb])); \
        const unsigned int keyI = (mm <= rf) ? 0u : key; \
        if (keyI > kI[fb]) kI[fb] = keyI; \
      } \
    } \
  }

  if (tbase + BT <= NP) { EPILOG(false) } else { EPILOG(true) }
#undef EPILOG

  // cross-lane reduce: lanes l and l^32 share j (disjoint t) -> one shfl step.
  uint2* red = (uint2*)sm.bufs[0];   // [2][128]; safe: bufs[0] reads ended at kb=2 barrier
#pragma unroll
  for (int fb = 0; fb < 2; ++fb) {
    const unsigned int oA = __shfl_xor(kA[fb], 32);
    const unsigned int oI = __shfl_xor(kI[fb], 32);
    if (oA > kA[fb]) kA[fb] = oA;
    if (oI > kI[fb]) kI[fb] = oI;
    if (kg == 0) red[wr * 128 + wc * 64 + fb * 32 + l31] = make_uint2(kA[fb], kI[fb]);
  }
  __syncthreads();
  if (tid < 128) {
    const int jg = jbase + tid;
    if (jg < NP) {
      uint2 p0 = red[tid];
      const uint2 p1 = red[128 + tid];
      if (p1.x > p0.x) p0.x = p1.x;
      if (p1.y > p0.y) p0.y = p1.y;
      partial[((size_t)b * NP + jg) * NTT + tt] = p0;
    }
  }
#undef STAGE
}

// ---------------- fused combine + per-point loss + recall (wave per point) ----------------
__global__ __launch_bounds__(256)
void k_loss(const unsigned short* __restrict__ refB, const unsigned short* __restrict__ tarB,
            const float* __restrict__ un, const uint2* __restrict__ partial,
            float* __restrict__ loss_arr, float* __restrict__ rec_arr) {
  const int w = threadIdx.x >> 6, lane = threadIdx.x & 63;
  const int n = blockIdx.x * 4 + w;
  const int b = blockIdx.y;
  const int bn = b * NP + n;
  unsigned int kA = 0u, kI = 0u;
  if (lane < NTT) {
    const uint2 p = partial[(size_t)bn * NTT + lane];
    kA = p.x; kI = p.y;
  }
#pragma unroll
  for (int d = 1; d < 64; d <<= 1) {
    const unsigned int oA = __shfl_xor(kA, d);
    const unsigned int oI = __shfl_xor(kI, d);
    if (oA > kA) kA = oA;
    if (oI > kI) kI = oI;
  }
  const int nn  = 8191 - (int)(kA & 0x1FFFu);
  const int neg = 8191 - (int)(kI & 0x1FFFu);
  const ushort4 rv = *(const ushort4*)(refB + ((size_t)b * NPAD + n) * CDIM + lane * 4);
  const ushort4 tv = *(const ushort4*)(tarB + ((size_t)b * NPAD + n) * CDIM + lane * 4);
  const ushort4 gv = *(const ushort4*)(tarB + ((size_t)b * NPAD + neg) * CDIM + lane * 4);
  float dp = 0.f, dn = 0.f, d;
  d = bf2f(rv.x) - bf2f(tv.x) + 1e-6f; dp += d * d;
  d = bf2f(rv.y) - bf2f(tv.y) + 1e-6f; dp += d * d;
  d = bf2f(rv.z) - bf2f(tv.z) + 1e-6f; dp += d * d;
  d = bf2f(rv.w) - bf2f(tv.w) + 1e-6f; dp += d * d;
  d = bf2f(rv.x) - bf2f(gv.x) + 1e-6f; dn += d * d;
  d = bf2f(rv.y) - bf2f(gv.y) + 1e-6f; dn += d * d;
  d = bf2f(rv.z) - bf2f(gv.z) + 1e-6f; dn += d * d;
  d = bf2f(rv.w) - bf2f(gv.w) + 1e-6f; dn += d * d;
#pragma unroll
  for (int off = 1; off < 64; off <<= 1) {
    dp += __shfl_xor(dp, off);
    dn += __shfl_xor(dn, off);
  }
  if (lane == 0) {
    const float loss = fmaxf(sqrtf(dp) - sqrtf(dn) + 0.2f, 0.f);
    const float* unb = un + (size_t)b * 2 * NP;
    const float rec = (unb[nn] == unb[n] && unb[NP + nn] == unb[NP + n]) ? 1.f : 0.f;
    loss_arr[bn] = loss;
    rec_arr[bn] = rec;
  }
}

// ---------------- final deterministic reduce ----------------
__global__ __launch_bounds__(256)
void k_finalize(const float* __restrict__ loss_arr, const float* __restrict__ rec_arr,
                float* __restrict__ out) {
  __shared__ float l[256], rr[256];
  float ls = 0.f, rs = 0.f;
  for (int i = threadIdx.x; i < BQ * NP; i += 256) { ls += loss_arr[i]; rs += rec_arr[i]; }
  l[threadIdx.x] = ls;
  rr[threadIdx.x] = rs;
  __syncthreads();
  for (int s = 128; s > 0; s >>= 1) {
    if (threadIdx.x < s) { l[threadIdx.x] += l[threadIdx.x + s]; rr[threadIdx.x] += rr[threadIdx.x + s]; }
    __syncthreads();
  }
  if (threadIdx.x == 0) {
    out[0] = l[0] / (float)(BQ * NP);
    out[1] = rr[0] / (float)(BQ * NP);
  }
}

extern "C" void kernel_launch(void* const* d_in, const int* in_sizes, int n_in,
                              void* d_out, int out_size, void* d_ws, size_t ws_size,
                              hipStream_t stream) {
  const float* src  = (const float*)d_in[0];
  const float* tgt  = (const float*)d_in[1];
  const float* spts = (const float*)d_in[2];
  const float* tpts = (const float*)d_in[3];
  const float* un   = (const float*)d_in[4];
  const int* relax  = (const int*)d_in[5];

  char* ws = (char*)d_ws;
  unsigned short* desT     = (unsigned short*)(ws + WS_DEST);
  uint2*          partial  = (uint2*)(ws + WS_PART);   // aliases desT (dead by then)
  unsigned short* refB     = (unsigned short*)(ws + WS_REFB);
  unsigned short* tarB     = (unsigned short*)(ws + WS_TARB);
  unsigned char*  refQ     = (unsigned char*)(ws + WS_REFQ);
  unsigned char*  tarQ     = (unsigned char*)(ws + WS_TARQ);
  float*          loss_arr = (float*)(ws + WS_LOSS);
  float*          rec_arr  = (float*)(ws + WS_REC);
  float*          out      = (float*)d_out;

  k_transpose<<<dim3(NP / 32, CDIM / 64, 8), dim3(32, 8), 0, stream>>>(src, tgt, desT);
  k_sample<<<dim3(NPAD / 4, BQ, 2), 256, 0, stream>>>(desT, spts, tpts, refB, tarB, refQ, tarQ);
  k_mfma_argmax<<<NBLK, 256, 0, stream>>>(tarQ, refQ, un, relax, partial);
  k_loss<<<dim3(NP / 4, BQ), 256, 0, stream>>>(refB, tarB, un, partial, loss_arr, rec_arr);
  k_finalize<<<1, 256, 0, stream>>>(loss_arr, rec_arr, out);
}

// Round 14
// 84.212 us; speedup vs baseline: 1.4212x; 1.2517x over previous
//
#include <hip/hip_runtime.h>
#include <cstdint>
#include <cstddef>

// Problem constants: B=4, C=256, H=60, W=80, N=4800
#define BQ 4
#define CDIM 256
#define HH 60
#define WW 80
#define NP 4800
#define NPAD 4864          // 38*128
#define BT 128             // tile rows (t, A = tar)
#define BJ 128             // tile cols (j, B = ref)
#define NTT 38             // t tiles (128)
#define NTJ 38             // j tiles (128)
#define NBLK (BQ * NTJ * NTT)   // 5776, %8==0
#define NLB 600            // k_loss blocks per batch (8 points each)

typedef float f32x4 __attribute__((ext_vector_type(4)));
typedef float f32x16 __attribute__((ext_vector_type(16)));
typedef int i32x4 __attribute__((ext_vector_type(4)));
typedef int i32x8 __attribute__((ext_vector_type(8)));
typedef unsigned short u16x8 __attribute__((ext_vector_type(8)));
typedef unsigned char u8x8 __attribute__((ext_vector_type(8)));

// ---------------- ws layout (bytes) ----------------
#define WS_DEST 0              // bf16 2*4*4800*256*2 = 19,660,800 (dead after k_sample)
#define WS_PART 0              // uint2 4*4800*38*8 = 5,836,800 (aliases desT)
#define WS_REFB 19660800       // bf16 4*4864*256*2 = 9,961,472 (for k_loss)
#define WS_TARB 29622272       // bf16                9,961,472
#define WS_REFQ 39583744       // fp8 4*4864*256 = 4,980,736 (for GEMM, plain k layout)
#define WS_TARQ 44564480       // fp8                4,980,736
#define WS_BPART 49545216      // float2 4*600 = 19,200 B (k_loss block partials)
// end 49,564,416

#define GLD16(dst, src) __builtin_amdgcn_global_load_lds( \
    (const __attribute__((address_space(1))) void*)(src), \
    (__attribute__((address_space(3))) void*)(dst), 16, 0, 0)

__device__ inline unsigned short f2bf(float f) {
  unsigned int u = __float_as_uint(f);
  return (unsigned short)((u + 0x7FFFu + ((u >> 16) & 1u)) >> 16);  // RNE
}
__device__ inline float bf2f(unsigned short s) {
  return __uint_as_float((unsigned int)s << 16);
}
// f32 -> OCP e4m3fn, RNE, clamp to +-448, subnormals handled
__device__ inline unsigned char f2e4m3(float x) {
  float ax = fminf(fabsf(x), 448.f);
  const unsigned int sign = (__float_as_uint(x) >> 24) & 0x80u;
  if (ax < 0.015625f) {                     // below 2^-6: subnormal (or carry to 0x08)
    const int M = (int)rintf(ax * 512.f);   // 0..8; 8 == 2^-6 encodes as E=1,M=0
    return (unsigned char)(sign | (unsigned int)M);
  }
  unsigned int u = __float_as_uint(ax);
  u += 0x7FFFFu + ((u >> 20) & 1u);         // RNE at mantissa bit 20 (carry ok)
  unsigned int e = (u >> 23) - 120u;        // exp bias 127 -> 7
  unsigned int m = (u >> 20) & 7u;
  if (e >= 16u) { e = 15u; m = 6u; }        // clamp to 448 (rounding overshoot)
  return (unsigned char)(sign | (e << 3) | m);
}

// ---------------- transpose des (C, HW) f32 -> (HW, C) bf16 ----------------
__global__ __launch_bounds__(256)
void k_transpose(const float* __restrict__ src, const float* __restrict__ tgt,
                 unsigned short* __restrict__ desT) {
  __shared__ float tile[64][33];
  const int z = blockIdx.z;  // tensor*4 + b
  const float* in = ((z >> 2) ? tgt : src) + (size_t)(z & 3) * CDIM * NP;
  unsigned short* out = desT + (size_t)z * NP * CDIM;
  const int hw0 = blockIdx.x * 32;
  const int c0 = blockIdx.y * 64;
  const int tx = threadIdx.x, ty = threadIdx.y;
#pragma unroll
  for (int q = 0; q < 8; ++q)
    tile[ty + q * 8][tx] = in[(size_t)(c0 + ty + q * 8) * NP + hw0 + tx];
  __syncthreads();
  const int lt = ty * 32 + tx;
  const int c2 = lt & 7;        // 8 channels each
  const int hw = lt >> 3;       // 0..31
  u16x8 o;
#pragma unroll
  for (int k = 0; k < 8; ++k) o[k] = f2bf(tile[c2 * 8 + k][hw]);
  *(u16x8*)(out + (size_t)(hw0 + hw) * CDIM + c0 + c2 * 8) = o;
}

// ---------------- bilinear sample + L2 normalize: 32 lanes/point, 16B reads ----------------
// Round-14: each 32-lane group handles one point (8 channels/lane, u16x8 = 16 B/lane
// corner reads -> half the VMEM instructions of the 64-lane/ushort4 version).
__global__ __launch_bounds__(256)
void k_sample(const unsigned short* __restrict__ desT,
              const float* __restrict__ spts, const float* __restrict__ tpts,
              unsigned short* __restrict__ refB, unsigned short* __restrict__ tarB,
              unsigned char* __restrict__ refQ, unsigned char* __restrict__ tarQ) {
  const int pg = threadIdx.x >> 5, l = threadIdx.x & 31;
  const int n = blockIdx.x * 8 + pg;        // 0..NPAD-1
  const int b = blockIdx.y;
  const int tensor = blockIdx.z;            // 0: ref, 1: tar
  unsigned short* outRowB = (tensor ? tarB : refB) + ((size_t)b * NPAD + n) * CDIM;
  unsigned char*  outRowQ = (tensor ? tarQ : refQ) + ((size_t)b * NPAD + n) * CDIM;
  const int c0 = l * 8;
  if (n >= NP) {  // zero pad rows (uniform per 32-group)
    *(u16x8*)(outRowB + c0) = (u16x8){0, 0, 0, 0, 0, 0, 0, 0};
    *(u8x8*)(outRowQ + c0) = (u8x8){0, 0, 0, 0, 0, 0, 0, 0};
    return;
  }
  const float* pts = (tensor ? tpts : spts) + ((size_t)b * NP + n) * 2;
  const float gx = pts[0], gy = pts[1];
  const float x = (gx + 1.f) * ((WW - 1) * 0.5f);
  const float y = (gy + 1.f) * ((HH - 1) * 0.5f);
  float x0f = fminf(fmaxf(floorf(x), 0.f), (float)(WW - 1));
  float y0f = fminf(fmaxf(floorf(y), 0.f), (float)(HH - 1));
  float x1f = fminf(x0f + 1.f, (float)(WW - 1));
  float y1f = fminf(y0f + 1.f, (float)(HH - 1));
  const float wx = x - x0f, wy = y - y0f;
  const int ix0 = (int)x0f, ix1 = (int)x1f, iy0 = (int)y0f, iy1 = (int)y1f;
  const unsigned short* base = desT + (size_t)(tensor * 4 + b) * NP * CDIM + c0;
  const u16x8 u00 = *(const u16x8*)(base + (size_t)(iy0 * WW + ix0) * CDIM);
  const u16x8 u01 = *(const u16x8*)(base + (size_t)(iy0 * WW + ix1) * CDIM);
  const u16x8 u10 = *(const u16x8*)(base + (size_t)(iy1 * WW + ix0) * CDIM);
  const u16x8 u11 = *(const u16x8*)(base + (size_t)(iy1 * WW + ix1) * CDIM);
  const float w00 = (1.f - wx) * (1.f - wy), w01 = wx * (1.f - wy);
  const float w10 = (1.f - wx) * wy,         w11 = wx * wy;
  float v[8];
  float sum = 0.f;
#pragma unroll
  for (int k = 0; k < 8; ++k) {
    v[k] = bf2f(u00[k]) * w00 + bf2f(u01[k]) * w01 + bf2f(u10[k]) * w10 + bf2f(u11[k]) * w11;
    const float s = v[k] + 1e-8f;
    sum += s * s;
  }
#pragma unroll
  for (int d = 1; d < 32; d <<= 1) sum += __shfl_xor(sum, d);  // stays in 32-group
  const float inv = 1.f / (sqrtf(sum) + 1e-8f);
  const float invq = inv * 16.f;   // scale into e4m3 normal range; dot' = 256*dot
  u16x8 ob;
  u8x8 oq;
#pragma unroll
  for (int k = 0; k < 8; ++k) {
    ob[k] = f2bf(v[k] * inv);
    oq[k] = f2e4m3(v[k] * invq);
  }
  *(u16x8*)(outRowB + c0) = ob;
  *(u8x8*)(outRowQ + c0) = oq;
}

// ---------------- MX-fp8 MFMA GEMM (128t x 128j, 32x32x64, unit scales) + dual argmax ----------------
// UNCHANGED from round 13 (proven 46.3 us): mfma_scale_f32_32x32x64_f8f6f4, unit e8m0
// scales, plain fp8 layout, proven slot-XOR swizzle, 4 blocks/CU, setprio around MFMA.
struct Smem {
  char bufs[2][16384];   // per buf: A [128][64B] @0, B [128][64B] @8192
  float2 tc2[128];       // t coords (x,y)
  float2 jc2[128];       // j coords (x,y)
};                       // 34,816 B -> 4 blocks/CU

__global__ __launch_bounds__(256, 4)
void k_mfma_argmax(const unsigned char* __restrict__ tarQ,
                   const unsigned char* __restrict__ refQ,
                   const float* __restrict__ un, const int* __restrict__ relax,
                   uint2* __restrict__ partial) {
  __shared__ Smem sm;
  const int tid = threadIdx.x;
  const int lane = tid & 63;
  const int wid = tid >> 6;

  // XCD swizzle (5776 % 8 == 0)
  const int bid = blockIdx.x;
  const int item = (bid & 7) * (NBLK / 8) + (bid >> 3);
  const int b = item / (NTJ * NTT);
  const int r2 = item - b * (NTJ * NTT);
  const int jt = r2 / NTT, tt = r2 % NTT;
  const int tbase = tt * BT, jbase = jt * BJ;
  const float* unb = un + (size_t)b * 2 * NP;

  // stage coords into LDS (before first barrier)
  if (tid < 128) {
    const int tg = (tbase + tid < NP) ? tbase + tid : NP - 1;
    sm.tc2[tid] = make_float2(unb[tg], unb[NP + tg]);
  } else {
    const int i2 = tid - 128;
    const int jg = (jbase + i2 < NP) ? jbase + i2 : NP - 1;
    sm.jc2[i2] = make_float2(unb[jg], unb[NP + jg]);
  }

  // staging: waves 0-1 -> A (64 rows each), waves 2-3 -> B (64 rows each)
  const char* aSrc = (const char*)(tarQ + ((size_t)b * NPAD + tbase) * CDIM);
  const char* bSrc = (const char*)(refQ + ((size_t)b * NPAD + jbase) * CDIM);
  const int srcSlot = ((lane & 3) ^ ((lane >> 3) & 3)) * 16;
  const char* gl; int ldsOff;
  if (wid < 2) {
    gl = aSrc + (size_t)(wid * 64 + (lane >> 2)) * 256 + srcSlot;
    ldsOff = wid * 4096;
  } else {
    gl = bSrc + (size_t)((wid - 2) * 64 + (lane >> 2)) * 256 + srcSlot;
    ldsOff = 8192 + (wid - 2) * 4096;
  }

#define STAGE(buf, kb) do { \
    char* ldst = sm.bufs[buf] + ldsOff; \
    const char* gsp = gl + (kb) * 64; \
    _Pragma("unroll") for (int qq = 0; qq < 4; ++qq) \
      GLD16(ldst + qq * 1024, gsp + (size_t)qq * 4096); \
  } while (0)

  const int wr = wid >> 1, wc = wid & 1;   // wave tile: 64t x 64j
  const int l31 = lane & 31, kg = lane >> 5;
  const int swm = (l31 >> 1) & 3;                 // read-side slot swizzle
  const int sx0 = ((2 * kg) ^ swm) << 4;
  const int sx1 = ((2 * kg + 1) ^ swm) << 4;

  f32x16 acc[2][2];
#pragma unroll
  for (int fa = 0; fa < 2; ++fa)
#pragma unroll
    for (int fb = 0; fb < 2; ++fb)
#pragma unroll
      for (int r = 0; r < 16; ++r) acc[fa][fb][r] = 0.f;

  // loop-invariant LDS read bases
  const char* aptr = sm.bufs[0] + (wr * 64 + l31) * 64;
  const char* bptr = sm.bufs[0] + 8192 + (wc * 64 + l31) * 64;

  STAGE(0, 0);
  __syncthreads();
#pragma unroll
  for (int kb = 0; kb < 4; ++kb) {   // K = 256 = 4 * 64
    const int bo = (kb & 1) * 16384;
    if (kb < 3) STAGE((kb & 1) ^ 1, kb + 1);   // issue next-tile loads before compute
    i32x8 aF[2], bF[2];
#pragma unroll
    for (int f = 0; f < 2; ++f) {
      const i32x4 alo = *(const i32x4*)(aptr + bo + f * 2048 + sx0);
      const i32x4 ahi = *(const i32x4*)(aptr + bo + f * 2048 + sx1);
      aF[f] = __builtin_shufflevector(alo, ahi, 0, 1, 2, 3, 4, 5, 6, 7);
      const i32x4 blo = *(const i32x4*)(bptr + bo + f * 2048 + sx0);
      const i32x4 bhi = *(const i32x4*)(bptr + bo + f * 2048 + sx1);
      bF[f] = __builtin_shufflevector(blo, bhi, 0, 1, 2, 3, 4, 5, 6, 7);
    }
    __builtin_amdgcn_s_setprio(1);
#pragma unroll
    for (int fa = 0; fa < 2; ++fa)
#pragma unroll
      for (int fb = 0; fb < 2; ++fb)
        acc[fa][fb] = __builtin_amdgcn_mfma_scale_f32_32x32x64_f8f6f4(
            aF[fa], bF[fb], acc[fa][fb], 0, 0,
            0, 0x7F7F7F7F, 0, 0x7F7F7F7F);   // fmt fp8/fp8, scales = 1.0
    __builtin_amdgcn_s_setprio(0);
    if (kb < 3) __syncthreads();   // kb3: no LDS reuse below (red is in bufs[0], reads ended kb2)
  }

  // ---- epilogue: packed-key dual argmax (u32: [31:13]=bits(acc+512), [12:0]=8191-t) ----
  const float rf = (float)relax[0];
  float jx[2], jy[2];
#pragma unroll
  for (int fb = 0; fb < 2; ++fb) {
    const float2 jj = sm.jc2[wc * 64 + fb * 32 + l31];
    jx[fb] = jj.x; jy[fb] = jj.y;
  }
  unsigned int kA[2] = {0u, 0u}, kI[2] = {0u, 0u};
  const unsigned int tinv0 = (unsigned int)(8191 - tbase);

#define EPILOG(TAIL) \
  _Pragma("unroll") for (int fa = 0; fa < 2; ++fa) { \
    _Pragma("unroll") for (int reg = 0; reg < 16; ++reg) { \
      const int tl = wr * 64 + fa * 32 + 4 * kg + (reg & 3) + 8 * (reg >> 2); \
      const float2 tj = sm.tc2[tl]; \
      const unsigned int tinv = tinv0 - tl; \
      _Pragma("unroll") for (int fb = 0; fb < 2; ++fb) { \
        unsigned int key = (__float_as_uint(acc[fa][fb][reg] + 512.f) & 0xFFFFE000u) | tinv; \
        if (TAIL && (tbase + tl >= NP)) key = 0u; \
        if (key > kA[fb]) kA[fb] = key; \
        const float mm = fmaxf(fabsf(tj.x - jx[fb]), fabsf(tj.y - jy[fb])); \
        const unsigned int keyI = (mm <= rf) ? 0u : key; \
        if (keyI > kI[fb]) kI[fb] = keyI; \
      } \
    } \
  }

  if (tbase + BT <= NP) { EPILOG(false) } else { EPILOG(true) }
#undef EPILOG

  // cross-lane reduce: lanes l and l^32 share j (disjoint t) -> one shfl step.
  uint2* red = (uint2*)sm.bufs[0];   // [2][128]; safe: bufs[0] reads ended at kb=2 barrier
#pragma unroll
  for (int fb = 0; fb < 2; ++fb) {
    const unsigned int oA = __shfl_xor(kA[fb], 32);
    const unsigned int oI = __shfl_xor(kI[fb], 32);
    if (oA > kA[fb]) kA[fb] = oA;
    if (oI > kI[fb]) kI[fb] = oI;
    if (kg == 0) red[wr * 128 + wc * 64 + fb * 32 + l31] = make_uint2(kA[fb], kI[fb]);
  }
  __syncthreads();
  if (tid < 128) {
    const int jg = jbase + tid;
    if (jg < NP) {
      uint2 p0 = red[tid];
      const uint2 p1 = red[128 + tid];
      if (p1.x > p0.x) p0.x = p1.x;
      if (p1.y > p0.y) p0.y = p1.y;
      partial[((size_t)b * NP + jg) * NTT + tt] = p0;
    }
  }
#undef STAGE
}

// ---------------- fused combine + loss + recall: 2 points/wave, block partials ----------------
// Round-14: 32-lane groups (u16x8 = 16 B/lane row reads), 8 points/block; block writes
// ONE float2 partial (sum of loss, sum of recall) -> finalize reads 19.2 KB not 154 KB.
__global__ __launch_bounds__(256)
void k_loss(const unsigned short* __restrict__ refB, const unsigned short* __restrict__ tarB,
            const float* __restrict__ un, const uint2* __restrict__ partial,
            float2* __restrict__ blockpart) {
  const int pg = threadIdx.x >> 5, l = threadIdx.x & 31;
  const int n = blockIdx.x * 8 + pg;
  const int b = blockIdx.y;
  const int bn = b * NP + n;
  unsigned int kA = 0u, kI = 0u;
  if (l < NTT) {
    const uint2 p = partial[(size_t)bn * NTT + l];
    kA = p.x; kI = p.y;
  }
#pragma unroll
  for (int d = 1; d < 32; d <<= 1) {   // stays within the 32-lane group
    const unsigned int oA = __shfl_xor(kA, d);
    const unsigned int oI = __shfl_xor(kI, d);
    if (oA > kA) kA = oA;
    if (oI > kI) kI = oI;
  }
  const int nn  = 8191 - (int)(kA & 0x1FFFu);
  const int neg = 8191 - (int)(kI & 0x1FFFu);
  const int c0 = l * 8;
  const u16x8 rv = *(const u16x8*)(refB + ((size_t)b * NPAD + n) * CDIM + c0);
  const u16x8 tv = *(const u16x8*)(tarB + ((size_t)b * NPAD + n) * CDIM + c0);
  const u16x8 gv = *(const u16x8*)(tarB + ((size_t)b * NPAD + neg) * CDIM + c0);
  float dp = 0.f, dn = 0.f;
#pragma unroll
  for (int k = 0; k < 8; ++k) {
    const float r = bf2f(rv[k]);
    float d1 = r - bf2f(tv[k]) + 1e-6f;
    float d2 = r - bf2f(gv[k]) + 1e-6f;
    dp += d1 * d1;
    dn += d2 * d2;
  }
#pragma unroll
  for (int off = 1; off < 32; off <<= 1) {
    dp += __shfl_xor(dp, off);
    dn += __shfl_xor(dn, off);
  }
  __shared__ float2 sred[8];
  if (l == 0) {
    const float loss = fmaxf(sqrtf(dp) - sqrtf(dn) + 0.2f, 0.f);
    const float* unb = un + (size_t)b * 2 * NP;
    const float rec = (unb[nn] == unb[n] && unb[NP + nn] == unb[NP + n]) ? 1.f : 0.f;
    sred[pg] = make_float2(loss, rec);
  }
  __syncthreads();
  if (threadIdx.x == 0) {
    float sl = 0.f, sr = 0.f;
#pragma unroll
    for (int g = 0; g < 8; ++g) { sl += sred[g].x; sr += sred[g].y; }
    blockpart[b * NLB + blockIdx.x] = make_float2(sl, sr);
  }
}

// ---------------- final deterministic reduce (19.2 KB input) ----------------
__global__ __launch_bounds__(256)
void k_finalize(const float2* __restrict__ blockpart, float* __restrict__ out) {
  __shared__ float l[256], rr[256];
  float ls = 0.f, rs = 0.f;
  for (int i = threadIdx.x; i < BQ * NLB; i += 256) {
    const float2 p = blockpart[i];
    ls += p.x; rs += p.y;
  }
  l[threadIdx.x] = ls;
  rr[threadIdx.x] = rs;
  __syncthreads();
  for (int s = 128; s > 0; s >>= 1) {
    if (threadIdx.x < s) { l[threadIdx.x] += l[threadIdx.x + s]; rr[threadIdx.x] += rr[threadIdx.x + s]; }
    __syncthreads();
  }
  if (threadIdx.x == 0) {
    out[0] = l[0] / (float)(BQ * NP);
    out[1] = rr[0] / (float)(BQ * NP);
  }
}

extern "C" void kernel_launch(void* const* d_in, const int* in_sizes, int n_in,
                              void* d_out, int out_size, void* d_ws, size_t ws_size,
                              hipStream_t stream) {
  const float* src  = (const float*)d_in[0];
  const float* tgt  = (const float*)d_in[1];
  const float* spts = (const float*)d_in[2];
  const float* tpts = (const float*)d_in[3];
  const float* un   = (const float*)d_in[4];
  const int* relax  = (const int*)d_in[5];

  char* ws = (char*)d_ws;
  unsigned short* desT      = (unsigned short*)(ws + WS_DEST);
  uint2*          partial   = (uint2*)(ws + WS_PART);   // aliases desT (dead by then)
  unsigned short* refB      = (unsigned short*)(ws + WS_REFB);
  unsigned short* tarB      = (unsigned short*)(ws + WS_TARB);
  unsigned char*  refQ      = (unsigned char*)(ws + WS_REFQ);
  unsigned char*  tarQ      = (unsigned char*)(ws + WS_TARQ);
  float2*         blockpart = (float2*)(ws + WS_BPART);
  float*          out       = (float*)d_out;

  k_transpose<<<dim3(NP / 32, CDIM / 64, 8), dim3(32, 8), 0, stream>>>(src, tgt, desT);
  k_sample<<<dim3(NPAD / 8, BQ, 2), 256, 0, stream>>>(desT, spts, tpts, refB, tarB, refQ, tarQ);
  k_mfma_argmax<<<NBLK, 256, 0, stream>>>(tarQ, refQ, un, relax, partial);
  k_loss<<<dim3(NLB, BQ), 256, 0, stream>>>(refB, tarB, un, partial, blockpart);
  k_finalize<<<1, 256, 0, stream>>>(blockpart, out);
}

// Round 15
// 83.939 us; speedup vs baseline: 1.4259x; 1.0032x over previous
//
#include <hip/hip_runtime.h>
#include <cstdint>
#include <cstddef>

// Problem constants: B=4, C=256, H=60, W=80, N=4800
#define BQ 4
#define CDIM 256
#define HH 60
#define WW 80
#define NP 4800
#define NPAD 4864          // 38*128
#define BT 128             // tile rows (t, A = tar)
#define BJ 128             // tile cols (j, B = ref)
#define NTT 38             // t tiles (128)
#define NTJ 38             // j tiles (128)
#define NBLK (BQ * NTJ * NTT)   // 5776, %8==0
#define NLB 600            // k_loss blocks per batch (8 points each)

typedef float f32x4 __attribute__((ext_vector_type(4)));
typedef float f32x16 __attribute__((ext_vector_type(16)));
typedef int i32x4 __attribute__((ext_vector_type(4)));
typedef int i32x8 __attribute__((ext_vector_type(8)));
typedef unsigned short u16x8 __attribute__((ext_vector_type(8)));
typedef unsigned char u8x8 __attribute__((ext_vector_type(8)));

// ---------------- ws layout (bytes) ----------------
#define WS_DEST 0              // bf16 2*4*4800*256*2 = 19,660,800 (dead after k_sample)
#define WS_PART 0              // uint2 4*4800*38*8 = 5,836,800 (aliases desT)
#define WS_REFB 19660800       // bf16 4*4864*256*2 = 9,961,472 (for k_loss)
#define WS_TARB 29622272       // bf16                9,961,472
#define WS_REFQ 39583744       // fp8 4*4864*256 = 4,980,736 (for GEMM, plain k layout)
#define WS_TARQ 44564480       // fp8                4,980,736
#define WS_BPART 49545216      // float2 4*600 = 19,200 B (k_loss block partials)
// end 49,564,416

#define GLD16(dst, src) __builtin_amdgcn_global_load_lds( \
    (const __attribute__((address_space(1))) void*)(src), \
    (__attribute__((address_space(3))) void*)(dst), 16, 0, 0)

__device__ inline unsigned short f2bf(float f) {
  unsigned int u = __float_as_uint(f);
  return (unsigned short)((u + 0x7FFFu + ((u >> 16) & 1u)) >> 16);  // RNE
}
__device__ inline float bf2f(unsigned short s) {
  return __uint_as_float((unsigned int)s << 16);
}
// f32 -> OCP e4m3fn, RNE, clamp to +-448, subnormals handled
__device__ inline unsigned char f2e4m3(float x) {
  float ax = fminf(fabsf(x), 448.f);
  const unsigned int sign = (__float_as_uint(x) >> 24) & 0x80u;
  if (ax < 0.015625f) {                     // below 2^-6: subnormal (or carry to 0x08)
    const int M = (int)rintf(ax * 512.f);   // 0..8; 8 == 2^-6 encodes as E=1,M=0
    return (unsigned char)(sign | (unsigned int)M);
  }
  unsigned int u = __float_as_uint(ax);
  u += 0x7FFFFu + ((u >> 20) & 1u);         // RNE at mantissa bit 20 (carry ok)
  unsigned int e = (u >> 23) - 120u;        // exp bias 127 -> 7
  unsigned int m = (u >> 20) & 7u;
  if (e >= 16u) { e = 15u; m = 6u; }        // clamp to 448 (rounding overshoot)
  return (unsigned char)(sign | (e << 3) | m);
}

// ---------------- transpose des (C, HW) f32 -> (HW, C) bf16 ----------------
__global__ __launch_bounds__(256)
void k_transpose(const float* __restrict__ src, const float* __restrict__ tgt,
                 unsigned short* __restrict__ desT) {
  __shared__ float tile[64][33];
  const int z = blockIdx.z;  // tensor*4 + b
  const float* in = ((z >> 2) ? tgt : src) + (size_t)(z & 3) * CDIM * NP;
  unsigned short* out = desT + (size_t)z * NP * CDIM;
  const int hw0 = blockIdx.x * 32;
  const int c0 = blockIdx.y * 64;
  const int tx = threadIdx.x, ty = threadIdx.y;
#pragma unroll
  for (int q = 0; q < 8; ++q)
    tile[ty + q * 8][tx] = in[(size_t)(c0 + ty + q * 8) * NP + hw0 + tx];
  __syncthreads();
  const int lt = ty * 32 + tx;
  const int c2 = lt & 7;        // 8 channels each
  const int hw = lt >> 3;       // 0..31
  u16x8 o;
#pragma unroll
  for (int k = 0; k < 8; ++k) o[k] = f2bf(tile[c2 * 8 + k][hw]);
  *(u16x8*)(out + (size_t)(hw0 + hw) * CDIM + c0 + c2 * 8) = o;
}

// ---------------- bilinear sample + L2 normalize: 32 lanes/point, 16B reads ----------------
__global__ __launch_bounds__(256)
void k_sample(const unsigned short* __restrict__ desT,
              const float* __restrict__ spts, const float* __restrict__ tpts,
              unsigned short* __restrict__ refB, unsigned short* __restrict__ tarB,
              unsigned char* __restrict__ refQ, unsigned char* __restrict__ tarQ) {
  const int pg = threadIdx.x >> 5, l = threadIdx.x & 31;
  const int n = blockIdx.x * 8 + pg;        // 0..NPAD-1
  const int b = blockIdx.y;
  const int tensor = blockIdx.z;            // 0: ref, 1: tar
  unsigned short* outRowB = (tensor ? tarB : refB) + ((size_t)b * NPAD + n) * CDIM;
  unsigned char*  outRowQ = (tensor ? tarQ : refQ) + ((size_t)b * NPAD + n) * CDIM;
  const int c0 = l * 8;
  if (n >= NP) {  // zero pad rows (uniform per 32-group)
    *(u16x8*)(outRowB + c0) = (u16x8){0, 0, 0, 0, 0, 0, 0, 0};
    *(u8x8*)(outRowQ + c0) = (u8x8){0, 0, 0, 0, 0, 0, 0, 0};
    return;
  }
  const float* pts = (tensor ? tpts : spts) + ((size_t)b * NP + n) * 2;
  const float gx = pts[0], gy = pts[1];
  const float x = (gx + 1.f) * ((WW - 1) * 0.5f);
  const float y = (gy + 1.f) * ((HH - 1) * 0.5f);
  float x0f = fminf(fmaxf(floorf(x), 0.f), (float)(WW - 1));
  float y0f = fminf(fmaxf(floorf(y), 0.f), (float)(HH - 1));
  float x1f = fminf(x0f + 1.f, (float)(WW - 1));
  float y1f = fminf(y0f + 1.f, (float)(HH - 1));
  const float wx = x - x0f, wy = y - y0f;
  const int ix0 = (int)x0f, ix1 = (int)x1f, iy0 = (int)y0f, iy1 = (int)y1f;
  const unsigned short* base = desT + (size_t)(tensor * 4 + b) * NP * CDIM + c0;
  const u16x8 u00 = *(const u16x8*)(base + (size_t)(iy0 * WW + ix0) * CDIM);
  const u16x8 u01 = *(const u16x8*)(base + (size_t)(iy0 * WW + ix1) * CDIM);
  const u16x8 u10 = *(const u16x8*)(base + (size_t)(iy1 * WW + ix0) * CDIM);
  const u16x8 u11 = *(const u16x8*)(base + (size_t)(iy1 * WW + ix1) * CDIM);
  const float w00 = (1.f - wx) * (1.f - wy), w01 = wx * (1.f - wy);
  const float w10 = (1.f - wx) * wy,         w11 = wx * wy;
  float v[8];
  float sum = 0.f;
#pragma unroll
  for (int k = 0; k < 8; ++k) {
    v[k] = bf2f(u00[k]) * w00 + bf2f(u01[k]) * w01 + bf2f(u10[k]) * w10 + bf2f(u11[k]) * w11;
    const float s = v[k] + 1e-8f;
    sum += s * s;
  }
#pragma unroll
  for (int d = 1; d < 32; d <<= 1) sum += __shfl_xor(sum, d);  // stays in 32-group
  const float inv = 1.f / (sqrtf(sum) + 1e-8f);
  const float invq = inv * 16.f;   // scale into e4m3 normal range; dot' = 256*dot
  u16x8 ob;
  u8x8 oq;
#pragma unroll
  for (int k = 0; k < 8; ++k) {
    ob[k] = f2bf(v[k] * inv);
    oq[k] = f2e4m3(v[k] * invq);
  }
  *(u16x8*)(outRowB + c0) = ob;
  *(u8x8*)(outRowQ + c0) = oq;
}

// ---------------- MX-fp8 MFMA GEMM (128t x 128j, 32x32x64, unit scales) + dual argmax ----------------
// Round-15 delta: extended LDS swizzle. Stored slot s of row r holds global slot
// s ^ ((r>>1)&3) ^ ((r>>4)&3). The old ((r>>1)&3)-only swizzle had period 8 in lane
// while row stride (64 B) = 16 banks, so lanes {l, l+8, l+16, l+24} of a kg-half hit
// IDENTICAL banks -> 4-way conflict (3.05M cycles, round 13/14). Adding row bits 4-5
// ((r>>4)&3 = qq at store [compile-time], = ((l31>>4)&1)|(f<<1) at read) leaves only
// the free 2-way (l, l+8) alias. Pure storage permutation - numerics unchanged.
struct Smem {
  char bufs[2][16384];   // per buf: A [128][64B] @0, B [128][64B] @8192
  float2 tc2[128];       // t coords (x,y)
  float2 jc2[128];       // j coords (x,y)
};                       // 34,816 B -> 4 blocks/CU

__global__ __launch_bounds__(256, 4)
void k_mfma_argmax(const unsigned char* __restrict__ tarQ,
                   const unsigned char* __restrict__ refQ,
                   const float* __restrict__ un, const int* __restrict__ relax,
                   uint2* __restrict__ partial) {
  __shared__ Smem sm;
  const int tid = threadIdx.x;
  const int lane = tid & 63;
  const int wid = tid >> 6;

  // XCD swizzle (5776 % 8 == 0)
  const int bid = blockIdx.x;
  const int item = (bid & 7) * (NBLK / 8) + (bid >> 3);
  const int b = item / (NTJ * NTT);
  const int r2 = item - b * (NTJ * NTT);
  const int jt = r2 / NTT, tt = r2 % NTT;
  const int tbase = tt * BT, jbase = jt * BJ;
  const float* unb = un + (size_t)b * 2 * NP;

  // stage coords into LDS (before first barrier)
  if (tid < 128) {
    const int tg = (tbase + tid < NP) ? tbase + tid : NP - 1;
    sm.tc2[tid] = make_float2(unb[tg], unb[NP + tg]);
  } else {
    const int i2 = tid - 128;
    const int jg = (jbase + i2 < NP) ? jbase + i2 : NP - 1;
    sm.jc2[i2] = make_float2(unb[jg], unb[NP + jg]);
  }

  // staging: waves 0-1 -> A (64 rows each), waves 2-3 -> B (64 rows each)
  // global rows are 256 B (fp8, plain k); kb selects a 64-B slice.
  // Source slot pre-swizzled per qq: (l&3) ^ ((l>>3)&3) ^ qq  (row bits 1-2 and 4-5).
  const char* aSrc = (const char*)(tarQ + ((size_t)b * NPAD + tbase) * CDIM);
  const char* bSrc = (const char*)(refQ + ((size_t)b * NPAD + jbase) * CDIM);
  const char* gl; int ldsOff;
  if (wid < 2) {
    gl = aSrc + (size_t)(wid * 64 + (lane >> 2)) * 256;
    ldsOff = wid * 4096;
  } else {
    gl = bSrc + (size_t)((wid - 2) * 64 + (lane >> 2)) * 256;
    ldsOff = 8192 + (wid - 2) * 4096;
  }
  const int slotBase = (lane & 3) ^ ((lane >> 3) & 3);

#define STAGE(buf, kb) do { \
    char* ldst = sm.bufs[buf] + ldsOff; \
    const char* gsp = gl + (kb) * 64; \
    _Pragma("unroll") for (int qq = 0; qq < 4; ++qq) \
      GLD16(ldst + qq * 1024, gsp + (size_t)qq * 4096 + ((slotBase ^ qq) * 16)); \
  } while (0)

  const int wr = wid >> 1, wc = wid & 1;   // wave tile: 64t x 64j
  const int l31 = lane & 31, kg = lane >> 5;
  const int swm = ((l31 >> 1) & 3) ^ ((l31 >> 4) & 1);   // read-side slot swizzle (row bits 1-2, 4)

  f32x16 acc[2][2];
#pragma unroll
  for (int fa = 0; fa < 2; ++fa)
#pragma unroll
    for (int fb = 0; fb < 2; ++fb)
#pragma unroll
      for (int r = 0; r < 16; ++r) acc[fa][fb][r] = 0.f;

  // loop-invariant LDS read bases
  const char* aptr = sm.bufs[0] + (wr * 64 + l31) * 64;
  const char* bptr = sm.bufs[0] + 8192 + (wc * 64 + l31) * 64;

  STAGE(0, 0);
  __syncthreads();
#pragma unroll
  for (int kb = 0; kb < 4; ++kb) {   // K = 256 = 4 * 64
    const int bo = (kb & 1) * 16384;
    if (kb < 3) STAGE((kb & 1) ^ 1, kb + 1);   // issue next-tile loads before compute
    i32x8 aF[2], bF[2];
#pragma unroll
    for (int f = 0; f < 2; ++f) {
      const int sx0 = (((2 * kg) ^ swm ^ (f << 1)) << 4);      // f = row bit 5
      const int sx1 = (((2 * kg + 1) ^ swm ^ (f << 1)) << 4);
      const i32x4 alo = *(const i32x4*)(aptr + bo + f * 2048 + sx0);
      const i32x4 ahi = *(const i32x4*)(aptr + bo + f * 2048 + sx1);
      aF[f] = __builtin_shufflevector(alo, ahi, 0, 1, 2, 3, 4, 5, 6, 7);
      const i32x4 blo = *(const i32x4*)(bptr + bo + f * 2048 + sx0);
      const i32x4 bhi = *(const i32x4*)(bptr + bo + f * 2048 + sx1);
      bF[f] = __builtin_shufflevector(blo, bhi, 0, 1, 2, 3, 4, 5, 6, 7);
    }
    __builtin_amdgcn_s_setprio(1);
#pragma unroll
    for (int fa = 0; fa < 2; ++fa)
#pragma unroll
      for (int fb = 0; fb < 2; ++fb)
        acc[fa][fb] = __builtin_amdgcn_mfma_scale_f32_32x32x64_f8f6f4(
            aF[fa], bF[fb], acc[fa][fb], 0, 0,
            0, 0x7F7F7F7F, 0, 0x7F7F7F7F);   // fmt fp8/fp8, scales = 1.0
    __builtin_amdgcn_s_setprio(0);
    if (kb < 3) __syncthreads();   // kb3: no LDS reuse below (red is in bufs[0], reads ended kb2)
  }

  // ---- epilogue: packed-key dual argmax (u32: [31:13]=bits(acc+512), [12:0]=8191-t) ----
  const float rf = (float)relax[0];
  float jx[2], jy[2];
#pragma unroll
  for (int fb = 0; fb < 2; ++fb) {
    const float2 jj = sm.jc2[wc * 64 + fb * 32 + l31];
    jx[fb] = jj.x; jy[fb] = jj.y;
  }
  unsigned int kA[2] = {0u, 0u}, kI[2] = {0u, 0u};
  const unsigned int tinv0 = (unsigned int)(8191 - tbase);

#define EPILOG(TAIL) \
  _Pragma("unroll") for (int fa = 0; fa < 2; ++fa) { \
    _Pragma("unroll") for (int reg = 0; reg < 16; ++reg) { \
      const int tl = wr * 64 + fa * 32 + 4 * kg + (reg & 3) + 8 * (reg >> 2); \
      const float2 tj = sm.tc2[tl]; \
      const unsigned int tinv = tinv0 - tl; \
      _Pragma("unroll") for (int fb = 0; fb < 2; ++fb) { \
        unsigned int key = (__float_as_uint(acc[fa][fb][reg] + 512.f) & 0xFFFFE000u) | tinv; \
        if (TAIL && (tbase + tl >= NP)) key = 0u; \
        if (key > kA[fb]) kA[fb] = key; \
        const float mm = fmaxf(fabsf(tj.x - jx[fb]), fabsf(tj.y - jy[fb])); \
        const unsigned int keyI = (mm <= rf) ? 0u : key; \
        if (keyI > kI[fb]) kI[fb] = keyI; \
      } \
    } \
  }

  if (tbase + BT <= NP) { EPILOG(false) } else { EPILOG(true) }
#undef EPILOG

  // cross-lane reduce: lanes l and l^32 share j (disjoint t) -> one shfl step.
  uint2* red = (uint2*)sm.bufs[0];   // [2][128]; safe: bufs[0] reads ended at kb=2 barrier
#pragma unroll
  for (int fb = 0; fb < 2; ++fb) {
    const unsigned int oA = __shfl_xor(kA[fb], 32);
    const unsigned int oI = __shfl_xor(kI[fb], 32);
    if (oA > kA[fb]) kA[fb] = oA;
    if (oI > kI[fb]) kI[fb] = oI;
    if (kg == 0) red[wr * 128 + wc * 64 + fb * 32 + l31] = make_uint2(kA[fb], kI[fb]);
  }
  __syncthreads();
  if (tid < 128) {
    const int jg = jbase + tid;
    if (jg < NP) {
      uint2 p0 = red[tid];
      const uint2 p1 = red[128 + tid];
      if (p1.x > p0.x) p0.x = p1.x;
      if (p1.y > p0.y) p0.y = p1.y;
      partial[((size_t)b * NP + jg) * NTT + tt] = p0;
    }
  }
#undef STAGE
}

// ---------------- fused combine + loss + recall: 2 points/wave, block partials ----------------
__global__ __launch_bounds__(256)
void k_loss(const unsigned short* __restrict__ refB, const unsigned short* __restrict__ tarB,
            const float* __restrict__ un, const uint2* __restrict__ partial,
            float2* __restrict__ blockpart) {
  const int pg = threadIdx.x >> 5, l = threadIdx.x & 31;
  const int n = blockIdx.x * 8 + pg;
  const int b = blockIdx.y;
  const int bn = b * NP + n;
  unsigned int kA = 0u, kI = 0u;
  if (l < NTT) {
    const uint2 p = partial[(size_t)bn * NTT + l];
    kA = p.x; kI = p.y;
  }
#pragma unroll
  for (int d = 1; d < 32; d <<= 1) {   // stays within the 32-lane group
    const unsigned int oA = __shfl_xor(kA, d);
    const unsigned int oI = __shfl_xor(kI, d);
    if (oA > kA) kA = oA;
    if (oI > kI) kI = oI;
  }
  const int nn  = 8191 - (int)(kA & 0x1FFFu);
  const int neg = 8191 - (int)(kI & 0x1FFFu);
  const int c0 = l * 8;
  const u16x8 rv = *(const u16x8*)(refB + ((size_t)b * NPAD + n) * CDIM + c0);
  const u16x8 tv = *(const u16x8*)(tarB + ((size_t)b * NPAD + n) * CDIM + c0);
  const u16x8 gv = *(const u16x8*)(tarB + ((size_t)b * NPAD + neg) * CDIM + c0);
  float dp = 0.f, dn = 0.f;
#pragma unroll
  for (int k = 0; k < 8; ++k) {
    const float r = bf2f(rv[k]);
    float d1 = r - bf2f(tv[k]) + 1e-6f;
    float d2 = r - bf2f(gv[k]) + 1e-6f;
    dp += d1 * d1;
    dn += d2 * d2;
  }
#pragma unroll
  for (int off = 1; off < 32; off <<= 1) {
    dp += __shfl_xor(dp, off);
    dn += __shfl_xor(dn, off);
  }
  __shared__ float2 sred[8];
  if (l == 0) {
    const float loss = fmaxf(sqrtf(dp) - sqrtf(dn) + 0.2f, 0.f);
    const float* unb = un + (size_t)b * 2 * NP;
    const float rec = (unb[nn] == unb[n] && unb[NP + nn] == unb[NP + n]) ? 1.f : 0.f;
    sred[pg] = make_float2(loss, rec);
  }
  __syncthreads();
  if (threadIdx.x == 0) {
    float sl = 0.f, sr = 0.f;
#pragma unroll
    for (int g = 0; g < 8; ++g) { sl += sred[g].x; sr += sred[g].y; }
    blockpart[b * NLB + blockIdx.x] = make_float2(sl, sr);
  }
}

// ---------------- final deterministic reduce (19.2 KB input) ----------------
__global__ __launch_bounds__(256)
void k_finalize(const float2* __restrict__ blockpart, float* __restrict__ out) {
  __shared__ float l[256], rr[256];
  float ls = 0.f, rs = 0.f;
  for (int i = threadIdx.x; i < BQ * NLB; i += 256) {
    const float2 p = blockpart[i];
    ls += p.x; rs += p.y;
  }
  l[threadIdx.x] = ls;
  rr[threadIdx.x] = rs;
  __syncthreads();
  for (int s = 128; s > 0; s >>= 1) {
    if (threadIdx.x < s) { l[threadIdx.x] += l[threadIdx.x + s]; rr[threadIdx.x] += rr[threadIdx.x + s]; }
    __syncthreads();
  }
  if (threadIdx.x == 0) {
    out[0] = l[0] / (float)(BQ * NP);
    out[1] = rr[0] / (float)(BQ * NP);
  }
}

extern "C" void kernel_launch(void* const* d_in, const int* in_sizes, int n_in,
                              void* d_out, int out_size, void* d_ws, size_t ws_size,
                              hipStream_t stream) {
  const float* src  = (const float*)d_in[0];
  const float* tgt  = (const float*)d_in[1];
  const float* spts = (const float*)d_in[2];
  const float* tpts = (const float*)d_in[3];
  const float* un   = (const float*)d_in[4];
  const int* relax  = (const int*)d_in[5];

  char* ws = (char*)d_ws;
  unsigned short* desT      = (unsigned short*)(ws + WS_DEST);
  uint2*          partial   = (uint2*)(ws + WS_PART);   // aliases desT (dead by then)
  unsigned short* refB      = (unsigned short*)(ws + WS_REFB);
  unsigned short* tarB      = (unsigned short*)(ws + WS_TARB);
  unsigned char*  refQ      = (unsigned char*)(ws + WS_REFQ);
  unsigned char*  tarQ      = (unsigned char*)(ws + WS_TARQ);
  float2*         blockpart = (float2*)(ws + WS_BPART);
  float*          out       = (float*)d_out;

  k_transpose<<<dim3(NP / 32, CDIM / 64, 8), dim3(32, 8), 0, stream>>>(src, tgt, desT);
  k_sample<<<dim3(NPAD / 8, BQ, 2), 256, 0, stream>>>(desT, spts, tpts, refB, tarB, refQ, tarQ);
  k_mfma_argmax<<<NBLK, 256, 0, stream>>>(tarQ, refQ, un, relax, partial);
  k_loss<<<dim3(NLB, BQ), 256, 0, stream>>>(refB, tarB, un, partial, blockpart);
  k_finalize<<<1, 256, 0, stream>>>(blockpart, out);
}